// Round 1
// baseline (446.314 us; speedup 1.0000x reference)
//
#include <hip/hip_runtime.h>
#include <hip/hip_bf16.h>

// ---------------------------------------------------------------------------
// SimplifiedGATBlock: 2-layer GAT, N=50000 nodes, E=800000 edges (+self loops)
// Layer1: IN=128 -> HEADS=4 x HID=32 (concat -> 128), ELU
// Layer2: 128 -> OUT=128 (1 head), ELU
// Strategy: counting-sort edges into dst-CSR once per launch, then
// wave-per-destination-node softmax-aggregation (no atomics in hot path).
// Softmax computed without max-subtraction (logits bounded ~ +/-5, fp32 safe;
// mathematically identical to the reference's max-shifted form).
// ---------------------------------------------------------------------------

static __device__ __forceinline__ float leaky02(float x) {
    return x > 0.f ? x : 0.2f * x;
}
static __device__ __forceinline__ float elu1(float x) {
    return x > 0.f ? x : __expf(x) - 1.f;
}

// ---------------- CSR build ----------------

__global__ void init_counts_kernel(int* __restrict__ cnt, int n) {
    int i = blockIdx.x * blockDim.x + threadIdx.x;
    if (i < n) cnt[i] = 1;  // self-loop contributes 1 incoming edge per node
}

__global__ void hist_kernel(const int* __restrict__ dst, int* __restrict__ cnt, int e) {
    int i = blockIdx.x * blockDim.x + threadIdx.x;
    if (i < e) atomicAdd(&cnt[dst[i]], 1);
}

// inclusive scan of 2048-element tiles; per-tile totals to sums[]
__global__ void scan_tile_kernel(const int* __restrict__ in, int* __restrict__ out,
                                 int* __restrict__ sums, int n) {
    __shared__ int sdata[256];
    int t = threadIdx.x;
    int base = blockIdx.x * 2048 + t * 8;
    int v[8];
    int run = 0;
#pragma unroll
    for (int i = 0; i < 8; ++i) {
        int idx = base + i;
        int x = (idx < n) ? in[idx] : 0;
        run += x;
        v[i] = run;
    }
    sdata[t] = run;
    __syncthreads();
    for (int off = 1; off < 256; off <<= 1) {
        int u = (t >= off) ? sdata[t - off] : 0;
        __syncthreads();
        sdata[t] += u;
        __syncthreads();
    }
    int excl = sdata[t] - run;
#pragma unroll
    for (int i = 0; i < 8; ++i) {
        int idx = base + i;
        if (idx < n) out[idx] = v[i] + excl;
    }
    if (t == 0) sums[blockIdx.x] = sdata[255];
}

// exclusive scan of up to 64 tile sums (single wave)
__global__ void scan_sums_kernel(int* __restrict__ sums, int nb) {
    int t = threadIdx.x;  // 64 threads
    int orig = (t < nb) ? sums[t] : 0;
    int v = orig;
#pragma unroll
    for (int off = 1; off < 64; off <<= 1) {
        int u = __shfl_up(v, off, 64);
        if (t >= off) v += u;
    }
    if (t < nb) sums[t] = v - orig;  // exclusive prefix
}

__global__ void scan_add_kernel(const int* __restrict__ incl, const int* __restrict__ sums,
                                int* __restrict__ row_ptr, int n) {
    int i = blockIdx.x * blockDim.x + threadIdx.x;
    if (i < n) row_ptr[i + 1] = incl[i] + sums[i >> 11];
    if (i == 0) row_ptr[0] = 0;
}

__global__ void cursor_copy_kernel(const int* __restrict__ row_ptr, int* __restrict__ cursor,
                                   int n) {
    int i = blockIdx.x * blockDim.x + threadIdx.x;
    if (i < n) cursor[i] = row_ptr[i];
}

__global__ void scatter_kernel(const int* __restrict__ src, const int* __restrict__ dst,
                               int* __restrict__ cursor, int* __restrict__ csr, int e) {
    int i = blockIdx.x * blockDim.x + threadIdx.x;
    if (i < e) {
        int d = dst[i];
        int p = atomicAdd(&cursor[d], 1);
        csr[p] = src[i];
    }
}

__global__ void scatter_self_kernel(int* __restrict__ cursor, int* __restrict__ csr, int n) {
    int i = blockIdx.x * blockDim.x + threadIdx.x;
    if (i < n) {
        int p = atomicAdd(&cursor[i], 1);
        csr[p] = i;
    }
}

// ---------------- dense GEMM: Y[n, 0..127] = X[n, 0..127] @ W[128][128] -----
// fp32 vector GEMM (no fp32 MFMA on CDNA4). 64-row x 128-col tile per block.
// LDS: X tile 64x64 (16KB) + W tile 64x128 (32KB) = 48KB.

__global__ __launch_bounds__(256) void gemm_nk128_kernel(const float* __restrict__ X,
                                                         const float* __restrict__ W,
                                                         float* __restrict__ Y, int nrows) {
    __shared__ float sX[64][64];
    __shared__ float sW[64][128];
    int t = threadIdx.x;
    int row0 = blockIdx.x * 64;
    float acc[8][4];
#pragma unroll
    for (int j = 0; j < 8; ++j)
#pragma unroll
        for (int q = 0; q < 4; ++q) acc[j][q] = 0.f;

    int tx = t & 31;  // col group: cols tx*4 .. tx*4+3
    int ty = t >> 5;  // 0..7; rows ty + 8*j

    for (int kc = 0; kc < 2; ++kc) {
        // stage X tile: 64 rows x 64 k
        {
            int tc = t & 15;
            int tr = t >> 4;
#pragma unroll
            for (int p = 0; p < 4; ++p) {
                int r = tr + p * 16;
                int gr = row0 + r;
                float4 v = make_float4(0.f, 0.f, 0.f, 0.f);
                if (gr < nrows) v = *(const float4*)(X + (size_t)gr * 128 + kc * 64 + tc * 4);
                *(float4*)(&sX[r][tc * 4]) = v;
            }
        }
        // stage W tile: 64 k x 128 c
        {
            int wc = t & 31;
            int wr = t >> 5;
#pragma unroll
            for (int p = 0; p < 8; ++p) {
                int k = wr + p * 8;
                *(float4*)(&sW[k][wc * 4]) = *(const float4*)(W + (size_t)(kc * 64 + k) * 128 + wc * 4);
            }
        }
        __syncthreads();
#pragma unroll 4
        for (int kk = 0; kk < 64; ++kk) {
            float4 wv = *(const float4*)(&sW[kk][tx * 4]);
#pragma unroll
            for (int j = 0; j < 8; ++j) {
                float xv = sX[ty + 8 * j][kk];
                acc[j][0] += xv * wv.x;
                acc[j][1] += xv * wv.y;
                acc[j][2] += xv * wv.z;
                acc[j][3] += xv * wv.w;
            }
        }
        __syncthreads();
    }
#pragma unroll
    for (int j = 0; j < 8; ++j) {
        int gr = row0 + ty + 8 * j;
        if (gr < nrows) {
            *(float4*)(Y + (size_t)gr * 128 + tx * 4) =
                make_float4(acc[j][0], acc[j][1], acc[j][2], acc[j][3]);
        }
    }
}

// ---------------- attention halves ----------------
// layer1: asrc[n][h] = sum_c H[n,h*32+c]*a_src[h*32+c]  (heads=4, reduce 16 lanes)
__global__ void alpha1_kernel(const float* __restrict__ H, const float* __restrict__ a_src,
                              const float* __restrict__ a_dst, float* __restrict__ asrc_out,
                              float* __restrict__ adst_out, int n) {
    int wave = (blockIdx.x * blockDim.x + threadIdx.x) >> 6;
    int lane = threadIdx.x & 63;
    if (wave >= n) return;
    int c = lane * 2;
    float2 hv = *(const float2*)(H + (size_t)wave * 128 + c);
    float2 as = *(const float2*)(a_src + c);
    float2 ad = *(const float2*)(a_dst + c);
    float ps = hv.x * as.x + hv.y * as.y;
    float pd = hv.x * ad.x + hv.y * ad.y;
#pragma unroll
    for (int off = 1; off <= 8; off <<= 1) {
        ps += __shfl_xor(ps, off, 64);
        pd += __shfl_xor(pd, off, 64);
    }
    if ((lane & 15) == 0) {
        int h = lane >> 4;
        asrc_out[wave * 4 + h] = ps;
        adst_out[wave * 4 + h] = pd;
    }
}

// layer2: heads=1, full-wave reduce
__global__ void alpha2_kernel(const float* __restrict__ H, const float* __restrict__ a_src,
                              const float* __restrict__ a_dst, float* __restrict__ asrc_out,
                              float* __restrict__ adst_out, int n) {
    int wave = (blockIdx.x * blockDim.x + threadIdx.x) >> 6;
    int lane = threadIdx.x & 63;
    if (wave >= n) return;
    int c = lane * 2;
    float2 hv = *(const float2*)(H + (size_t)wave * 128 + c);
    float2 as = *(const float2*)(a_src + c);
    float2 ad = *(const float2*)(a_dst + c);
    float ps = hv.x * as.x + hv.y * as.y;
    float pd = hv.x * ad.x + hv.y * ad.y;
#pragma unroll
    for (int off = 1; off <= 32; off <<= 1) {
        ps += __shfl_xor(ps, off, 64);
        pd += __shfl_xor(pd, off, 64);
    }
    if (lane == 0) {
        asrc_out[wave] = ps;
        adst_out[wave] = pd;
    }
}

// ---------------- softmax aggregation ----------------
// wave per destination node; lane owns channels 2*lane, 2*lane+1
__global__ void agg1_kernel(const float* __restrict__ H, const float* __restrict__ asrc,
                            const float* __restrict__ adst, const int* __restrict__ row_ptr,
                            const int* __restrict__ csr, const float* __restrict__ bias,
                            float* __restrict__ out, int n) {
    int wave = (blockIdx.x * blockDim.x + threadIdx.x) >> 6;
    int lane = threadIdx.x & 63;
    if (wave >= n) return;
    int c = lane * 2;
    int h = lane >> 4;  // head of both channels (head stride 32)
    float adh = adst[wave * 4 + h];
    int e0 = row_ptr[wave];
    int e1 = row_ptr[wave + 1];
    float den = 0.f, acc0 = 0.f, acc1 = 0.f;
    for (int e = e0; e < e1; ++e) {
        int s = csr[e];
        float w = __expf(leaky02(asrc[s * 4 + h] + adh));
        den += w;
        float2 hv = *(const float2*)(H + (size_t)s * 128 + c);
        acc0 += w * hv.x;
        acc1 += w * hv.y;
    }
    float inv = 1.f / (den + 1e-16f);
    float o0 = elu1(acc0 * inv + bias[c]);
    float o1 = elu1(acc1 * inv + bias[c + 1]);
    *(float2*)(out + (size_t)wave * 128 + c) = make_float2(o0, o1);
}

__global__ void agg2_kernel(const float* __restrict__ H, const float* __restrict__ asrc,
                            const float* __restrict__ adst, const int* __restrict__ row_ptr,
                            const int* __restrict__ csr, const float* __restrict__ bias,
                            float* __restrict__ out, int n) {
    int wave = (blockIdx.x * blockDim.x + threadIdx.x) >> 6;
    int lane = threadIdx.x & 63;
    if (wave >= n) return;
    int c = lane * 2;
    float adh = adst[wave];
    int e0 = row_ptr[wave];
    int e1 = row_ptr[wave + 1];
    float den = 0.f, acc0 = 0.f, acc1 = 0.f;
    for (int e = e0; e < e1; ++e) {
        int s = csr[e];
        float w = __expf(leaky02(asrc[s] + adh));
        den += w;
        float2 hv = *(const float2*)(H + (size_t)s * 128 + c);
        acc0 += w * hv.x;
        acc1 += w * hv.y;
    }
    float inv = 1.f / (den + 1e-16f);
    float o0 = elu1(acc0 * inv + bias[c]);
    float o1 = elu1(acc1 * inv + bias[c + 1]);
    *(float2*)(out + (size_t)wave * 128 + c) = make_float2(o0, o1);
}

// ---------------- host ----------------

extern "C" void kernel_launch(void* const* d_in, const int* in_sizes, int n_in,
                              void* d_out, int out_size, void* d_ws, size_t ws_size,
                              hipStream_t stream) {
    const float* x       = (const float*)d_in[0];
    const int*   eidx    = (const int*)d_in[1];
    const float* W1      = (const float*)d_in[2];
    const float* a_src1  = (const float*)d_in[3];
    const float* a_dst1  = (const float*)d_in[4];
    const float* b1      = (const float*)d_in[5];
    const float* W2      = (const float*)d_in[6];
    const float* a_src2  = (const float*)d_in[7];
    const float* a_dst2  = (const float*)d_in[8];
    const float* b2      = (const float*)d_in[9];
    float* out = (float*)d_out;

    const int N = in_sizes[0] / 128;  // 50000
    const int E = in_sizes[1] / 2;    // 800000
    const int* src = eidx;
    const int* dst = eidx + E;

    // workspace carve-up (~31.5 MB)
    char* w = (char*)d_ws;
    float* bufH = (float*)w;   w += (size_t)N * 128 * sizeof(float);
    float* asrc = (float*)w;   w += (size_t)N * 4 * sizeof(float);
    float* adst = (float*)w;   w += (size_t)N * 4 * sizeof(float);
    int* cnt     = (int*)w;    w += (size_t)N * sizeof(int);
    int* incl    = (int*)w;    w += (size_t)N * sizeof(int);
    int* row_ptr = (int*)w;    w += (size_t)(N + 1) * sizeof(int);
    int* cursor  = (int*)w;    w += (size_t)N * sizeof(int);
    int* sums    = (int*)w;    w += 64 * sizeof(int);
    int* csr     = (int*)w;    w += (size_t)(E + N) * sizeof(int);

    const int ntiles = (N + 2047) / 2048;
    dim3 b256(256);
    dim3 gN((N + 255) / 256);
    dim3 gE((E + 255) / 256);
    dim3 gWave((N + 3) / 4);          // wave-per-node kernels (4 waves/block)
    dim3 gGemm((N + 63) / 64);

    // ---- CSR build (counting sort by dst, self-loops included) ----
    hipLaunchKernelGGL(init_counts_kernel, gN, b256, 0, stream, cnt, N);
    hipLaunchKernelGGL(hist_kernel, gE, b256, 0, stream, dst, cnt, E);
    hipLaunchKernelGGL(scan_tile_kernel, dim3(ntiles), b256, 0, stream, cnt, incl, sums, N);
    hipLaunchKernelGGL(scan_sums_kernel, dim3(1), dim3(64), 0, stream, sums, ntiles);
    hipLaunchKernelGGL(scan_add_kernel, gN, b256, 0, stream, incl, sums, row_ptr, N);
    hipLaunchKernelGGL(cursor_copy_kernel, gN, b256, 0, stream, row_ptr, cursor, N);
    hipLaunchKernelGGL(scatter_kernel, gE, b256, 0, stream, src, dst, cursor, csr, E);
    hipLaunchKernelGGL(scatter_self_kernel, gN, b256, 0, stream, cursor, csr, N);

    // ---- layer 1 ----
    hipLaunchKernelGGL(gemm_nk128_kernel, gGemm, b256, 0, stream, x, W1, bufH, N);
    hipLaunchKernelGGL(alpha1_kernel, gWave, b256, 0, stream, bufH, a_src1, a_dst1, asrc, adst, N);
    // writes ELU(concat + b1) into d_out (used as intermediate h1 storage)
    hipLaunchKernelGGL(agg1_kernel, gWave, b256, 0, stream, bufH, asrc, adst, row_ptr, csr, b1,
                       out, N);

    // ---- layer 2 ----
    hipLaunchKernelGGL(gemm_nk128_kernel, gGemm, b256, 0, stream, out, W2, bufH, N);
    hipLaunchKernelGGL(alpha2_kernel, gWave, b256, 0, stream, bufH, a_src2, a_dst2, asrc, adst, N);
    hipLaunchKernelGGL(agg2_kernel, gWave, b256, 0, stream, bufH, asrc, adst, row_ptr, csr, b2,
                       out, N);
}

// Round 2
// 340.079 us; speedup vs baseline: 1.3124x; 1.3124x over previous
//
#include <hip/hip_runtime.h>
#include <hip/hip_bf16.h>

// ---------------------------------------------------------------------------
// SimplifiedGATBlock: 2-layer GAT, N=50000 nodes, E=800000 edges (+self loops)
// R2: agg kernels are latency-bound gathers (R1: VALUBusy 28%, hbm 30%).
//   (a) 4x edge-loop unroll for memory-level parallelism
//   (b) fp16 feature table for the gather (halves bytes; err ~5e-4 << margin)
// ---------------------------------------------------------------------------

typedef _Float16 half2_t __attribute__((ext_vector_type(2)));
typedef _Float16 half4_t __attribute__((ext_vector_type(4)));

static __device__ __forceinline__ float leaky02(float x) {
    return x > 0.f ? x : 0.2f * x;
}
static __device__ __forceinline__ float elu1(float x) {
    return x > 0.f ? x : __expf(x) - 1.f;
}

// ---------------- CSR build ----------------

__global__ void init_counts_kernel(int* __restrict__ cnt, int n) {
    int i = blockIdx.x * blockDim.x + threadIdx.x;
    if (i < n) cnt[i] = 1;  // self-loop contributes 1 incoming edge per node
}

__global__ void hist_kernel(const int* __restrict__ dst, int* __restrict__ cnt, int e) {
    int i = blockIdx.x * blockDim.x + threadIdx.x;
    if (i < e) atomicAdd(&cnt[dst[i]], 1);
}

// inclusive scan of 2048-element tiles; per-tile totals to sums[]
__global__ void scan_tile_kernel(const int* __restrict__ in, int* __restrict__ out,
                                 int* __restrict__ sums, int n) {
    __shared__ int sdata[256];
    int t = threadIdx.x;
    int base = blockIdx.x * 2048 + t * 8;
    int v[8];
    int run = 0;
#pragma unroll
    for (int i = 0; i < 8; ++i) {
        int idx = base + i;
        int x = (idx < n) ? in[idx] : 0;
        run += x;
        v[i] = run;
    }
    sdata[t] = run;
    __syncthreads();
    for (int off = 1; off < 256; off <<= 1) {
        int u = (t >= off) ? sdata[t - off] : 0;
        __syncthreads();
        sdata[t] += u;
        __syncthreads();
    }
    int excl = sdata[t] - run;
#pragma unroll
    for (int i = 0; i < 8; ++i) {
        int idx = base + i;
        if (idx < n) out[idx] = v[i] + excl;
    }
    if (t == 0) sums[blockIdx.x] = sdata[255];
}

// exclusive scan of up to 64 tile sums (single wave)
__global__ void scan_sums_kernel(int* __restrict__ sums, int nb) {
    int t = threadIdx.x;  // 64 threads
    int orig = (t < nb) ? sums[t] : 0;
    int v = orig;
#pragma unroll
    for (int off = 1; off < 64; off <<= 1) {
        int u = __shfl_up(v, off, 64);
        if (t >= off) v += u;
    }
    if (t < nb) sums[t] = v - orig;  // exclusive prefix
}

__global__ void scan_add_kernel(const int* __restrict__ incl, const int* __restrict__ sums,
                                int* __restrict__ row_ptr, int n) {
    int i = blockIdx.x * blockDim.x + threadIdx.x;
    if (i < n) row_ptr[i + 1] = incl[i] + sums[i >> 11];
    if (i == 0) row_ptr[0] = 0;
}

__global__ void cursor_copy_kernel(const int* __restrict__ row_ptr, int* __restrict__ cursor,
                                   int n) {
    int i = blockIdx.x * blockDim.x + threadIdx.x;
    if (i < n) cursor[i] = row_ptr[i];
}

__global__ void scatter_kernel(const int* __restrict__ src, const int* __restrict__ dst,
                               int* __restrict__ cursor, int* __restrict__ csr, int e) {
    int i = blockIdx.x * blockDim.x + threadIdx.x;
    if (i < e) {
        int d = dst[i];
        int p = atomicAdd(&cursor[d], 1);
        csr[p] = src[i];
    }
}

__global__ void scatter_self_kernel(int* __restrict__ cursor, int* __restrict__ csr, int n) {
    int i = blockIdx.x * blockDim.x + threadIdx.x;
    if (i < n) {
        int p = atomicAdd(&cursor[i], 1);
        csr[p] = i;
    }
}

// ---------------- dense GEMM: Y16[n,0..127] = fp16(X[n,0..127] @ W[128][128])
// fp32 vector GEMM (no fp32 MFMA on CDNA4). 64-row x 128-col tile per block.
// LDS: X tile 64x64 (16KB) + W tile 64x128 (32KB) = 48KB.
// Output fp16 only: consumers are the alpha dots and the edge gather, both
// tolerant of 2^-11 relative rounding.

__global__ __launch_bounds__(256) void gemm_nk128_kernel(const float* __restrict__ X,
                                                         const float* __restrict__ W,
                                                         _Float16* __restrict__ Y16,
                                                         int nrows) {
    __shared__ float sX[64][64];
    __shared__ float sW[64][128];
    int t = threadIdx.x;
    int row0 = blockIdx.x * 64;
    float acc[8][4];
#pragma unroll
    for (int j = 0; j < 8; ++j)
#pragma unroll
        for (int q = 0; q < 4; ++q) acc[j][q] = 0.f;

    int tx = t & 31;  // col group: cols tx*4 .. tx*4+3
    int ty = t >> 5;  // 0..7; rows ty + 8*j

    for (int kc = 0; kc < 2; ++kc) {
        {
            int tc = t & 15;
            int tr = t >> 4;
#pragma unroll
            for (int p = 0; p < 4; ++p) {
                int r = tr + p * 16;
                int gr = row0 + r;
                float4 v = make_float4(0.f, 0.f, 0.f, 0.f);
                if (gr < nrows) v = *(const float4*)(X + (size_t)gr * 128 + kc * 64 + tc * 4);
                *(float4*)(&sX[r][tc * 4]) = v;
            }
        }
        {
            int wc = t & 31;
            int wr = t >> 5;
#pragma unroll
            for (int p = 0; p < 8; ++p) {
                int k = wr + p * 8;
                *(float4*)(&sW[k][wc * 4]) = *(const float4*)(W + (size_t)(kc * 64 + k) * 128 + wc * 4);
            }
        }
        __syncthreads();
#pragma unroll 4
        for (int kk = 0; kk < 64; ++kk) {
            float4 wv = *(const float4*)(&sW[kk][tx * 4]);
#pragma unroll
            for (int j = 0; j < 8; ++j) {
                float xv = sX[ty + 8 * j][kk];
                acc[j][0] += xv * wv.x;
                acc[j][1] += xv * wv.y;
                acc[j][2] += xv * wv.z;
                acc[j][3] += xv * wv.w;
            }
        }
        __syncthreads();
    }
#pragma unroll
    for (int j = 0; j < 8; ++j) {
        int gr = row0 + ty + 8 * j;
        if (gr < nrows) {
            half4_t hv;
            hv.x = (_Float16)acc[j][0];
            hv.y = (_Float16)acc[j][1];
            hv.z = (_Float16)acc[j][2];
            hv.w = (_Float16)acc[j][3];
            *(half4_t*)(Y16 + (size_t)gr * 128 + tx * 4) = hv;
        }
    }
}

// ---------------- attention halves (read fp16 features) ----------------
__global__ void alpha1_kernel(const _Float16* __restrict__ H16, const float* __restrict__ a_src,
                              const float* __restrict__ a_dst, float* __restrict__ asrc_out,
                              float* __restrict__ adst_out, int n) {
    int wave = (blockIdx.x * blockDim.x + threadIdx.x) >> 6;
    int lane = threadIdx.x & 63;
    if (wave >= n) return;
    int c = lane * 2;
    half2_t hv = *(const half2_t*)(H16 + (size_t)wave * 128 + c);
    float2 as = *(const float2*)(a_src + c);
    float2 ad = *(const float2*)(a_dst + c);
    float hx = (float)hv.x, hy = (float)hv.y;
    float ps = hx * as.x + hy * as.y;
    float pd = hx * ad.x + hy * ad.y;
#pragma unroll
    for (int off = 1; off <= 8; off <<= 1) {
        ps += __shfl_xor(ps, off, 64);
        pd += __shfl_xor(pd, off, 64);
    }
    if ((lane & 15) == 0) {
        int h = lane >> 4;
        asrc_out[wave * 4 + h] = ps;
        adst_out[wave * 4 + h] = pd;
    }
}

__global__ void alpha2_kernel(const _Float16* __restrict__ H16, const float* __restrict__ a_src,
                              const float* __restrict__ a_dst, float* __restrict__ asrc_out,
                              float* __restrict__ adst_out, int n) {
    int wave = (blockIdx.x * blockDim.x + threadIdx.x) >> 6;
    int lane = threadIdx.x & 63;
    if (wave >= n) return;
    int c = lane * 2;
    half2_t hv = *(const half2_t*)(H16 + (size_t)wave * 128 + c);
    float2 as = *(const float2*)(a_src + c);
    float2 ad = *(const float2*)(a_dst + c);
    float hx = (float)hv.x, hy = (float)hv.y;
    float ps = hx * as.x + hy * as.y;
    float pd = hx * ad.x + hy * ad.y;
#pragma unroll
    for (int off = 1; off <= 32; off <<= 1) {
        ps += __shfl_xor(ps, off, 64);
        pd += __shfl_xor(pd, off, 64);
    }
    if (lane == 0) {
        asrc_out[wave] = ps;
        adst_out[wave] = pd;
    }
}

// ---------------- softmax aggregation (4x unrolled, fp16 gather) ----------
// wave per destination node; lane owns channels 2*lane, 2*lane+1

__global__ __launch_bounds__(256) void agg1_kernel(
    const _Float16* __restrict__ H16, const float* __restrict__ asrc,
    const float* __restrict__ adst, const int* __restrict__ row_ptr,
    const int* __restrict__ csr, const float* __restrict__ bias,
    float* __restrict__ out, int n) {
    int wave = (blockIdx.x * blockDim.x + threadIdx.x) >> 6;
    int lane = threadIdx.x & 63;
    if (wave >= n) return;
    int c = lane * 2;
    int h = lane >> 4;  // head of both channels (head stride 32)
    float adh = adst[wave * 4 + h];
    int e0 = row_ptr[wave];
    int e1 = row_ptr[wave + 1];
    float den = 0.f, acc0 = 0.f, acc1 = 0.f;
    int e = e0;
    for (; e + 4 <= e1; e += 4) {
        int s0 = csr[e + 0], s1 = csr[e + 1], s2 = csr[e + 2], s3 = csr[e + 3];
        float l0 = asrc[s0 * 4 + h];
        float l1 = asrc[s1 * 4 + h];
        float l2 = asrc[s2 * 4 + h];
        float l3 = asrc[s3 * 4 + h];
        half2_t g0 = *(const half2_t*)(H16 + (size_t)s0 * 128 + c);
        half2_t g1 = *(const half2_t*)(H16 + (size_t)s1 * 128 + c);
        half2_t g2 = *(const half2_t*)(H16 + (size_t)s2 * 128 + c);
        half2_t g3 = *(const half2_t*)(H16 + (size_t)s3 * 128 + c);
        float w0 = __expf(leaky02(l0 + adh));
        float w1 = __expf(leaky02(l1 + adh));
        float w2 = __expf(leaky02(l2 + adh));
        float w3 = __expf(leaky02(l3 + adh));
        den += (w0 + w1) + (w2 + w3);
        acc0 += w0 * (float)g0.x + w1 * (float)g1.x + w2 * (float)g2.x + w3 * (float)g3.x;
        acc1 += w0 * (float)g0.y + w1 * (float)g1.y + w2 * (float)g2.y + w3 * (float)g3.y;
    }
    for (; e < e1; ++e) {
        int s = csr[e];
        float w = __expf(leaky02(asrc[s * 4 + h] + adh));
        half2_t g = *(const half2_t*)(H16 + (size_t)s * 128 + c);
        den += w;
        acc0 += w * (float)g.x;
        acc1 += w * (float)g.y;
    }
    float inv = 1.f / (den + 1e-16f);
    float o0 = elu1(acc0 * inv + bias[c]);
    float o1 = elu1(acc1 * inv + bias[c + 1]);
    *(float2*)(out + (size_t)wave * 128 + c) = make_float2(o0, o1);
}

__global__ __launch_bounds__(256) void agg2_kernel(
    const _Float16* __restrict__ H16, const float* __restrict__ asrc,
    const float* __restrict__ adst, const int* __restrict__ row_ptr,
    const int* __restrict__ csr, const float* __restrict__ bias,
    float* __restrict__ out, int n) {
    int wave = (blockIdx.x * blockDim.x + threadIdx.x) >> 6;
    int lane = threadIdx.x & 63;
    if (wave >= n) return;
    int c = lane * 2;
    float adh = adst[wave];
    int e0 = row_ptr[wave];
    int e1 = row_ptr[wave + 1];
    float den = 0.f, acc0 = 0.f, acc1 = 0.f;
    int e = e0;
    for (; e + 4 <= e1; e += 4) {
        int s0 = csr[e + 0], s1 = csr[e + 1], s2 = csr[e + 2], s3 = csr[e + 3];
        float l0 = asrc[s0];
        float l1 = asrc[s1];
        float l2 = asrc[s2];
        float l3 = asrc[s3];
        half2_t g0 = *(const half2_t*)(H16 + (size_t)s0 * 128 + c);
        half2_t g1 = *(const half2_t*)(H16 + (size_t)s1 * 128 + c);
        half2_t g2 = *(const half2_t*)(H16 + (size_t)s2 * 128 + c);
        half2_t g3 = *(const half2_t*)(H16 + (size_t)s3 * 128 + c);
        float w0 = __expf(leaky02(l0 + adh));
        float w1 = __expf(leaky02(l1 + adh));
        float w2 = __expf(leaky02(l2 + adh));
        float w3 = __expf(leaky02(l3 + adh));
        den += (w0 + w1) + (w2 + w3);
        acc0 += w0 * (float)g0.x + w1 * (float)g1.x + w2 * (float)g2.x + w3 * (float)g3.x;
        acc1 += w0 * (float)g0.y + w1 * (float)g1.y + w2 * (float)g2.y + w3 * (float)g3.y;
    }
    for (; e < e1; ++e) {
        int s = csr[e];
        float w = __expf(leaky02(asrc[s] + adh));
        half2_t g = *(const half2_t*)(H16 + (size_t)s * 128 + c);
        den += w;
        acc0 += w * (float)g.x;
        acc1 += w * (float)g.y;
    }
    float inv = 1.f / (den + 1e-16f);
    float o0 = elu1(acc0 * inv + bias[c]);
    float o1 = elu1(acc1 * inv + bias[c + 1]);
    *(float2*)(out + (size_t)wave * 128 + c) = make_float2(o0, o1);
}

// ---------------- host ----------------

extern "C" void kernel_launch(void* const* d_in, const int* in_sizes, int n_in,
                              void* d_out, int out_size, void* d_ws, size_t ws_size,
                              hipStream_t stream) {
    const float* x       = (const float*)d_in[0];
    const int*   eidx    = (const int*)d_in[1];
    const float* W1      = (const float*)d_in[2];
    const float* a_src1  = (const float*)d_in[3];
    const float* a_dst1  = (const float*)d_in[4];
    const float* b1      = (const float*)d_in[5];
    const float* W2      = (const float*)d_in[6];
    const float* a_src2  = (const float*)d_in[7];
    const float* a_dst2  = (const float*)d_in[8];
    const float* b2      = (const float*)d_in[9];
    float* out = (float*)d_out;

    const int N = in_sizes[0] / 128;  // 50000
    const int E = in_sizes[1] / 2;    // 800000
    const int* src = eidx;
    const int* dst = eidx + E;

    // workspace carve-up (~19 MB)
    char* w = (char*)d_ws;
    _Float16* bufH16 = (_Float16*)w; w += (size_t)N * 128 * sizeof(_Float16);
    float* asrc = (float*)w;   w += (size_t)N * 4 * sizeof(float);
    float* adst = (float*)w;   w += (size_t)N * 4 * sizeof(float);
    int* cnt     = (int*)w;    w += (size_t)N * sizeof(int);
    int* incl    = (int*)w;    w += (size_t)N * sizeof(int);
    int* row_ptr = (int*)w;    w += (size_t)(N + 1) * sizeof(int);
    int* cursor  = (int*)w;    w += (size_t)N * sizeof(int);
    int* sums    = (int*)w;    w += 64 * sizeof(int);
    int* csr     = (int*)w;    w += (size_t)(E + N) * sizeof(int);

    const int ntiles = (N + 2047) / 2048;
    dim3 b256(256);
    dim3 gN((N + 255) / 256);
    dim3 gE((E + 255) / 256);
    dim3 gWave((N + 3) / 4);          // wave-per-node kernels (4 waves/block)
    dim3 gGemm((N + 63) / 64);

    // ---- CSR build (counting sort by dst, self-loops included) ----
    hipLaunchKernelGGL(init_counts_kernel, gN, b256, 0, stream, cnt, N);
    hipLaunchKernelGGL(hist_kernel, gE, b256, 0, stream, dst, cnt, E);
    hipLaunchKernelGGL(scan_tile_kernel, dim3(ntiles), b256, 0, stream, cnt, incl, sums, N);
    hipLaunchKernelGGL(scan_sums_kernel, dim3(1), dim3(64), 0, stream, sums, ntiles);
    hipLaunchKernelGGL(scan_add_kernel, gN, b256, 0, stream, incl, sums, row_ptr, N);
    hipLaunchKernelGGL(cursor_copy_kernel, gN, b256, 0, stream, row_ptr, cursor, N);
    hipLaunchKernelGGL(scatter_kernel, gE, b256, 0, stream, src, dst, cursor, csr, E);
    hipLaunchKernelGGL(scatter_self_kernel, gN, b256, 0, stream, cursor, csr, N);

    // ---- layer 1 ----
    hipLaunchKernelGGL(gemm_nk128_kernel, gGemm, b256, 0, stream, x, W1, bufH16, N);
    hipLaunchKernelGGL(alpha1_kernel, gWave, b256, 0, stream, bufH16, a_src1, a_dst1, asrc, adst, N);
    hipLaunchKernelGGL(agg1_kernel, gWave, b256, 0, stream, bufH16, asrc, adst, row_ptr, csr, b1,
                       out, N);

    // ---- layer 2 ----
    hipLaunchKernelGGL(gemm_nk128_kernel, gGemm, b256, 0, stream, out, W2, bufH16, N);
    hipLaunchKernelGGL(alpha2_kernel, gWave, b256, 0, stream, bufH16, a_src2, a_dst2, asrc, adst, N);
    hipLaunchKernelGGL(agg2_kernel, gWave, b256, 0, stream, bufH16, asrc, adst, row_ptr, csr, b2,
                       out, N);
}

// Round 3
// 321.410 us; speedup vs baseline: 1.3886x; 1.0581x over previous
//
#include <hip/hip_runtime.h>
#include <hip/hip_bf16.h>

// ---------------------------------------------------------------------------
// SimplifiedGATBlock: 2-layer GAT, N=50000, E=800000 (+self loops)
// R3: (a) scatter fused into MFMA gemm1 (scatter is 0.4% VALU, 52MB random
//     writes -> hide behind compute); (b) fp16 MFMA GEMMs (16x16x32_f16,
//     A frags straight from global, B from pre-transposed fp16 Wt);
//     (c) agg1 emits fp16 h1 for gemm2.
// ---------------------------------------------------------------------------

typedef _Float16 half2_t __attribute__((ext_vector_type(2)));
typedef _Float16 f16x8 __attribute__((ext_vector_type(8)));
typedef float f32x4 __attribute__((ext_vector_type(4)));

static __device__ __forceinline__ float leaky02(float x) {
    return x > 0.f ? x : 0.2f * x;
}
static __device__ __forceinline__ float elu1(float x) {
    return x > 0.f ? x : __expf(x) - 1.f;
}

// ---------------- init counts + W1/W2 fp16 transpose (fused) ----------------
// blocks [0, nInit): cnt[i] = 1 (self-loop).  blocks [nInit, nInit+128):
// Wt[n][k] = (fp16) W[k][n] for both weight matrices (16384 elems each).

__global__ void init_prep_kernel(int* __restrict__ cnt, int n,
                                 const float* __restrict__ W1,
                                 const float* __restrict__ W2,
                                 _Float16* __restrict__ Wt1,
                                 _Float16* __restrict__ Wt2, int nInit) {
    int b = blockIdx.x;
    int t = threadIdx.x;
    if (b < nInit) {
        int i = b * 256 + t;
        if (i < n) cnt[i] = 1;
    } else {
        int idx = (b - nInit) * 256 + t;  // 0..32767
        int which = idx >> 14;
        int r = idx & 16383;
        int nc = r >> 7, k = r & 127;
        if (which == 0)
            Wt1[(size_t)nc * 128 + k] = (_Float16)W1[(size_t)k * 128 + nc];
        else
            Wt2[(size_t)nc * 128 + k] = (_Float16)W2[(size_t)k * 128 + nc];
    }
}

__global__ void hist_kernel(const int* __restrict__ dst, int* __restrict__ cnt, int e) {
    int i = blockIdx.x * blockDim.x + threadIdx.x;
    if (i < e) atomicAdd(&cnt[dst[i]], 1);
}

// inclusive scan of 2048-element tiles; per-tile totals to sums[]
__global__ void scan_tile_kernel(const int* __restrict__ in, int* __restrict__ out,
                                 int* __restrict__ sums, int n) {
    __shared__ int sdata[256];
    int t = threadIdx.x;
    int base = blockIdx.x * 2048 + t * 8;
    int v[8];
    int run = 0;
#pragma unroll
    for (int i = 0; i < 8; ++i) {
        int idx = base + i;
        int x = (idx < n) ? in[idx] : 0;
        run += x;
        v[i] = run;
    }
    sdata[t] = run;
    __syncthreads();
    for (int off = 1; off < 256; off <<= 1) {
        int u = (t >= off) ? sdata[t - off] : 0;
        __syncthreads();
        sdata[t] += u;
        __syncthreads();
    }
    int excl = sdata[t] - run;
#pragma unroll
    for (int i = 0; i < 8; ++i) {
        int idx = base + i;
        if (idx < n) out[idx] = v[i] + excl;
    }
    if (t == 0) sums[blockIdx.x] = sdata[255];
}

// exclusive scan of up to 64 tile sums (single wave)
__global__ void scan_sums_kernel(int* __restrict__ sums, int nb) {
    int t = threadIdx.x;  // 64 threads
    int orig = (t < nb) ? sums[t] : 0;
    int v = orig;
#pragma unroll
    for (int off = 1; off < 64; off <<= 1) {
        int u = __shfl_up(v, off, 64);
        if (t >= off) v += u;
    }
    if (t < nb) sums[t] = v - orig;  // exclusive prefix
}

// row_ptr[i+1] = incl-scan(i); cursor[i] = row_ptr[i]   (merged)
__global__ void scan_finish_kernel(const int* __restrict__ incl, const int* __restrict__ sums,
                                   int* __restrict__ row_ptr, int* __restrict__ cursor, int n) {
    int i = blockIdx.x * blockDim.x + threadIdx.x;
    if (i < n) {
        row_ptr[i + 1] = incl[i] + sums[i >> 11];
        cursor[i] = (i == 0) ? 0 : incl[i - 1] + sums[(i - 1) >> 11];
    }
    if (i == 0) row_ptr[0] = 0;
}

// ---------------- fused: MFMA gemm1 (fp32 A) + edge scatter + self scatter --
// gemm blocks: 64 rows x 128 cols per block, 4 waves, wave = 16 rows.
// mfma_f32_16x16x32_f16: A[m=lane&15][k=(lane>>4)*8+j], B[k][n=lane&15],
// C: col=lane&15, row=(lane>>4)*4+reg.

__global__ __launch_bounds__(256) void gemm1_fused_kernel(
    const float* __restrict__ X, const _Float16* __restrict__ Wt,
    _Float16* __restrict__ H16, int nrows, const int* __restrict__ src,
    const int* __restrict__ dst, int* __restrict__ cursor, int* __restrict__ csr,
    int E, int nGemm, int nScat) {
    int b = blockIdx.x;
    int t = threadIdx.x;
    if (b < nGemm) {
        int wave = t >> 6, lane = t & 63;
        int m = lane & 15, q = lane >> 4;
        int arow = b * 64 + wave * 16 + m;
        bool rowok = arow < nrows;
        const float* xr = X + (size_t)arow * 128;
        f16x8 afrag[4];
#pragma unroll
        for (int s = 0; s < 4; ++s) {
            float4 v0 = make_float4(0.f, 0.f, 0.f, 0.f);
            float4 v1 = make_float4(0.f, 0.f, 0.f, 0.f);
            if (rowok) {
                v0 = *(const float4*)(xr + s * 32 + q * 8);
                v1 = *(const float4*)(xr + s * 32 + q * 8 + 4);
            }
            f16x8 a;
            a[0] = (_Float16)v0.x; a[1] = (_Float16)v0.y;
            a[2] = (_Float16)v0.z; a[3] = (_Float16)v0.w;
            a[4] = (_Float16)v1.x; a[5] = (_Float16)v1.y;
            a[6] = (_Float16)v1.z; a[7] = (_Float16)v1.w;
            afrag[s] = a;
        }
#pragma unroll
        for (int c = 0; c < 8; ++c) {
            f32x4 acc = {0.f, 0.f, 0.f, 0.f};
#pragma unroll
            for (int s = 0; s < 4; ++s) {
                f16x8 bfrag = *(const f16x8*)(Wt + (size_t)(c * 16 + m) * 128 + s * 32 + q * 8);
                acc = __builtin_amdgcn_mfma_f32_16x16x32_f16(afrag[s], bfrag, acc, 0, 0, 0);
            }
#pragma unroll
            for (int r = 0; r < 4; ++r) {
                int orow = b * 64 + wave * 16 + q * 4 + r;
                if (orow < nrows)
                    H16[(size_t)orow * 128 + c * 16 + m] = (_Float16)acc[r];
            }
        }
    } else if (b < nGemm + nScat) {
        int base = (b - nGemm) * 1024 + t;
#pragma unroll
        for (int j = 0; j < 4; ++j) {
            int i = base + j * 256;
            if (i < E) {
                int d = dst[i];
                int p = atomicAdd(&cursor[d], 1);
                csr[p] = src[i];
            }
        }
    } else {
        int base = (b - nGemm - nScat) * 1024 + t;
#pragma unroll
        for (int j = 0; j < 4; ++j) {
            int i = base + j * 256;
            if (i < nrows) {
                int p = atomicAdd(&cursor[i], 1);
                csr[p] = i;
            }
        }
    }
}

// ---------------- MFMA gemm2 (fp16 A) ----------------
__global__ __launch_bounds__(256) void gemm2_mfma_kernel(
    const _Float16* __restrict__ A16, const _Float16* __restrict__ Wt,
    _Float16* __restrict__ H16, int nrows) {
    int b = blockIdx.x;
    int t = threadIdx.x;
    int wave = t >> 6, lane = t & 63;
    int m = lane & 15, q = lane >> 4;
    int arow = b * 64 + wave * 16 + m;
    bool rowok = arow < nrows;
    const _Float16* ar = A16 + (size_t)arow * 128;
    f16x8 afrag[4];
#pragma unroll
    for (int s = 0; s < 4; ++s) {
        f16x8 a = {};
        if (rowok) a = *(const f16x8*)(ar + s * 32 + q * 8);
        afrag[s] = a;
    }
#pragma unroll
    for (int c = 0; c < 8; ++c) {
        f32x4 acc = {0.f, 0.f, 0.f, 0.f};
#pragma unroll
        for (int s = 0; s < 4; ++s) {
            f16x8 bfrag = *(const f16x8*)(Wt + (size_t)(c * 16 + m) * 128 + s * 32 + q * 8);
            acc = __builtin_amdgcn_mfma_f32_16x16x32_f16(afrag[s], bfrag, acc, 0, 0, 0);
        }
#pragma unroll
        for (int r = 0; r < 4; ++r) {
            int orow = b * 64 + wave * 16 + q * 4 + r;
            if (orow < nrows)
                H16[(size_t)orow * 128 + c * 16 + m] = (_Float16)acc[r];
        }
    }
}

// ---------------- attention halves (read fp16 features) ----------------
__global__ void alpha1_kernel(const _Float16* __restrict__ H16, const float* __restrict__ a_src,
                              const float* __restrict__ a_dst, float* __restrict__ asrc_out,
                              float* __restrict__ adst_out, int n) {
    int wave = (blockIdx.x * blockDim.x + threadIdx.x) >> 6;
    int lane = threadIdx.x & 63;
    if (wave >= n) return;
    int c = lane * 2;
    half2_t hv = *(const half2_t*)(H16 + (size_t)wave * 128 + c);
    float2 as = *(const float2*)(a_src + c);
    float2 ad = *(const float2*)(a_dst + c);
    float hx = (float)hv.x, hy = (float)hv.y;
    float ps = hx * as.x + hy * as.y;
    float pd = hx * ad.x + hy * ad.y;
#pragma unroll
    for (int off = 1; off <= 8; off <<= 1) {
        ps += __shfl_xor(ps, off, 64);
        pd += __shfl_xor(pd, off, 64);
    }
    if ((lane & 15) == 0) {
        int h = lane >> 4;
        asrc_out[wave * 4 + h] = ps;
        adst_out[wave * 4 + h] = pd;
    }
}

__global__ void alpha2_kernel(const _Float16* __restrict__ H16, const float* __restrict__ a_src,
                              const float* __restrict__ a_dst, float* __restrict__ asrc_out,
                              float* __restrict__ adst_out, int n) {
    int wave = (blockIdx.x * blockDim.x + threadIdx.x) >> 6;
    int lane = threadIdx.x & 63;
    if (wave >= n) return;
    int c = lane * 2;
    half2_t hv = *(const half2_t*)(H16 + (size_t)wave * 128 + c);
    float2 as = *(const float2*)(a_src + c);
    float2 ad = *(const float2*)(a_dst + c);
    float hx = (float)hv.x, hy = (float)hv.y;
    float ps = hx * as.x + hy * as.y;
    float pd = hx * ad.x + hy * ad.y;
#pragma unroll
    for (int off = 1; off <= 32; off <<= 1) {
        ps += __shfl_xor(ps, off, 64);
        pd += __shfl_xor(pd, off, 64);
    }
    if (lane == 0) {
        asrc_out[wave] = ps;
        adst_out[wave] = pd;
    }
}

// ---------------- softmax aggregation (4x unrolled, fp16 gather) ----------
// wave per destination node; lane owns channels 2*lane, 2*lane+1
// agg1 writes fp16 h1 (consumed only by gemm2's A operand).

__global__ __launch_bounds__(256) void agg1_kernel(
    const _Float16* __restrict__ H16, const float* __restrict__ asrc,
    const float* __restrict__ adst, const int* __restrict__ row_ptr,
    const int* __restrict__ csr, const float* __restrict__ bias,
    _Float16* __restrict__ out16, int n) {
    int wave = (blockIdx.x * blockDim.x + threadIdx.x) >> 6;
    int lane = threadIdx.x & 63;
    if (wave >= n) return;
    int c = lane * 2;
    int h = lane >> 4;  // head of both channels (head stride 32)
    float adh = adst[wave * 4 + h];
    int e0 = row_ptr[wave];
    int e1 = row_ptr[wave + 1];
    float den = 0.f, acc0 = 0.f, acc1 = 0.f;
    int e = e0;
    for (; e + 4 <= e1; e += 4) {
        int s0 = csr[e + 0], s1 = csr[e + 1], s2 = csr[e + 2], s3 = csr[e + 3];
        float l0 = asrc[s0 * 4 + h];
        float l1 = asrc[s1 * 4 + h];
        float l2 = asrc[s2 * 4 + h];
        float l3 = asrc[s3 * 4 + h];
        half2_t g0 = *(const half2_t*)(H16 + (size_t)s0 * 128 + c);
        half2_t g1 = *(const half2_t*)(H16 + (size_t)s1 * 128 + c);
        half2_t g2 = *(const half2_t*)(H16 + (size_t)s2 * 128 + c);
        half2_t g3 = *(const half2_t*)(H16 + (size_t)s3 * 128 + c);
        float w0 = __expf(leaky02(l0 + adh));
        float w1 = __expf(leaky02(l1 + adh));
        float w2 = __expf(leaky02(l2 + adh));
        float w3 = __expf(leaky02(l3 + adh));
        den += (w0 + w1) + (w2 + w3);
        acc0 += w0 * (float)g0.x + w1 * (float)g1.x + w2 * (float)g2.x + w3 * (float)g3.x;
        acc1 += w0 * (float)g0.y + w1 * (float)g1.y + w2 * (float)g2.y + w3 * (float)g3.y;
    }
    for (; e < e1; ++e) {
        int s = csr[e];
        float w = __expf(leaky02(asrc[s * 4 + h] + adh));
        half2_t g = *(const half2_t*)(H16 + (size_t)s * 128 + c);
        den += w;
        acc0 += w * (float)g.x;
        acc1 += w * (float)g.y;
    }
    float inv = 1.f / (den + 1e-16f);
    half2_t o;
    o.x = (_Float16)elu1(acc0 * inv + bias[c]);
    o.y = (_Float16)elu1(acc1 * inv + bias[c + 1]);
    *(half2_t*)(out16 + (size_t)wave * 128 + c) = o;
}

__global__ __launch_bounds__(256) void agg2_kernel(
    const _Float16* __restrict__ H16, const float* __restrict__ asrc,
    const float* __restrict__ adst, const int* __restrict__ row_ptr,
    const int* __restrict__ csr, const float* __restrict__ bias,
    float* __restrict__ out, int n) {
    int wave = (blockIdx.x * blockDim.x + threadIdx.x) >> 6;
    int lane = threadIdx.x & 63;
    if (wave >= n) return;
    int c = lane * 2;
    float adh = adst[wave];
    int e0 = row_ptr[wave];
    int e1 = row_ptr[wave + 1];
    float den = 0.f, acc0 = 0.f, acc1 = 0.f;
    int e = e0;
    for (; e + 4 <= e1; e += 4) {
        int s0 = csr[e + 0], s1 = csr[e + 1], s2 = csr[e + 2], s3 = csr[e + 3];
        float l0 = asrc[s0];
        float l1 = asrc[s1];
        float l2 = asrc[s2];
        float l3 = asrc[s3];
        half2_t g0 = *(const half2_t*)(H16 + (size_t)s0 * 128 + c);
        half2_t g1 = *(const half2_t*)(H16 + (size_t)s1 * 128 + c);
        half2_t g2 = *(const half2_t*)(H16 + (size_t)s2 * 128 + c);
        half2_t g3 = *(const half2_t*)(H16 + (size_t)s3 * 128 + c);
        float w0 = __expf(leaky02(l0 + adh));
        float w1 = __expf(leaky02(l1 + adh));
        float w2 = __expf(leaky02(l2 + adh));
        float w3 = __expf(leaky02(l3 + adh));
        den += (w0 + w1) + (w2 + w3);
        acc0 += w0 * (float)g0.x + w1 * (float)g1.x + w2 * (float)g2.x + w3 * (float)g3.x;
        acc1 += w0 * (float)g0.y + w1 * (float)g1.y + w2 * (float)g2.y + w3 * (float)g3.y;
    }
    for (; e < e1; ++e) {
        int s = csr[e];
        float w = __expf(leaky02(asrc[s] + adh));
        half2_t g = *(const half2_t*)(H16 + (size_t)s * 128 + c);
        den += w;
        acc0 += w * (float)g.x;
        acc1 += w * (float)g.y;
    }
    float inv = 1.f / (den + 1e-16f);
    float o0 = elu1(acc0 * inv + bias[c]);
    float o1 = elu1(acc1 * inv + bias[c + 1]);
    *(float2*)(out + (size_t)wave * 128 + c) = make_float2(o0, o1);
}

// ---------------- host ----------------

extern "C" void kernel_launch(void* const* d_in, const int* in_sizes, int n_in,
                              void* d_out, int out_size, void* d_ws, size_t ws_size,
                              hipStream_t stream) {
    const float* x       = (const float*)d_in[0];
    const int*   eidx    = (const int*)d_in[1];
    const float* W1      = (const float*)d_in[2];
    const float* a_src1  = (const float*)d_in[3];
    const float* a_dst1  = (const float*)d_in[4];
    const float* b1      = (const float*)d_in[5];
    const float* W2      = (const float*)d_in[6];
    const float* a_src2  = (const float*)d_in[7];
    const float* a_dst2  = (const float*)d_in[8];
    const float* b2      = (const float*)d_in[9];
    float* out = (float*)d_out;

    const int N = in_sizes[0] / 128;  // 50000
    const int E = in_sizes[1] / 2;    // 800000
    const int* src = eidx;
    const int* dst = eidx + E;

    // workspace carve-up (~31.5 MB)
    char* w = (char*)d_ws;
    _Float16* bufH16 = (_Float16*)w; w += (size_t)N * 128 * sizeof(_Float16);
    _Float16* bufA16 = (_Float16*)w; w += (size_t)N * 128 * sizeof(_Float16);
    _Float16* Wt1    = (_Float16*)w; w += (size_t)128 * 128 * sizeof(_Float16);
    _Float16* Wt2    = (_Float16*)w; w += (size_t)128 * 128 * sizeof(_Float16);
    float* asrc = (float*)w;   w += (size_t)N * 4 * sizeof(float);
    float* adst = (float*)w;   w += (size_t)N * 4 * sizeof(float);
    int* cnt     = (int*)w;    w += (size_t)N * sizeof(int);
    int* incl    = (int*)w;    w += (size_t)N * sizeof(int);
    int* row_ptr = (int*)w;    w += (size_t)(N + 1) * sizeof(int);
    int* cursor  = (int*)w;    w += (size_t)N * sizeof(int);
    int* sums    = (int*)w;    w += 64 * sizeof(int);
    int* csr     = (int*)w;    w += (size_t)(E + N) * sizeof(int);

    const int ntiles = (N + 2047) / 2048;  // 25
    dim3 b256(256);
    dim3 gN((N + 255) / 256);
    dim3 gE((E + 255) / 256);
    dim3 gWave((N + 3) / 4);          // wave-per-node kernels (4 waves/block)
    const int nGemm = (N + 63) / 64;         // 782
    const int nScat = (E + 1023) / 1024;     // 782
    const int nSelf = (N + 1023) / 1024;     // 49
    const int nInit = (N + 255) / 256;       // 196

    // ---- CSR prefix chain + weight prep ----
    hipLaunchKernelGGL(init_prep_kernel, dim3(nInit + 128), b256, 0, stream, cnt, N, W1, W2,
                       Wt1, Wt2, nInit);
    hipLaunchKernelGGL(hist_kernel, gE, b256, 0, stream, dst, cnt, E);
    hipLaunchKernelGGL(scan_tile_kernel, dim3(ntiles), b256, 0, stream, cnt, incl, sums, N);
    hipLaunchKernelGGL(scan_sums_kernel, dim3(1), dim3(64), 0, stream, sums, ntiles);
    hipLaunchKernelGGL(scan_finish_kernel, gN, b256, 0, stream, incl, sums, row_ptr, cursor, N);

    // ---- layer 1: gemm1 + scatter fused ----
    hipLaunchKernelGGL(gemm1_fused_kernel, dim3(nGemm + nScat + nSelf), b256, 0, stream, x, Wt1,
                       bufH16, N, src, dst, cursor, csr, E, nGemm, nScat);
    hipLaunchKernelGGL(alpha1_kernel, gWave, b256, 0, stream, bufH16, a_src1, a_dst1, asrc, adst, N);
    hipLaunchKernelGGL(agg1_kernel, gWave, b256, 0, stream, bufH16, asrc, adst, row_ptr, csr, b1,
                       bufA16, N);

    // ---- layer 2 ----
    hipLaunchKernelGGL(gemm2_mfma_kernel, dim3(nGemm), b256, 0, stream, bufA16, Wt2, bufH16, N);
    hipLaunchKernelGGL(alpha2_kernel, gWave, b256, 0, stream, bufH16, a_src2, a_dst2, asrc, adst, N);
    hipLaunchKernelGGL(agg2_kernel, gWave, b256, 0, stream, bufH16, asrc, adst, row_ptr, csr, b2,
                       out, N);
}

// Round 4
// 296.732 us; speedup vs baseline: 1.5041x; 1.0832x over previous
//
#include <hip/hip_runtime.h>
#include <hip/hip_bf16.h>

// ---------------------------------------------------------------------------
// SimplifiedGATBlock: 2-layer GAT, N=50000, E=800000 (+self loops)
// R4: (a) XCD-partitioned hist + scatter (range = blockIdx%8) -> csr/cursor
//     slices stay in one XCD's L2; kills the 51MB random-write amplification
//     that made R3's scatter 60us. (b) agg kernels: 2 nodes/wave, 4 ch/lane
//     (half4 gather) -> per-edge VALU overhead halved, 2x edge MLP.
// ---------------------------------------------------------------------------

typedef _Float16 half2_t __attribute__((ext_vector_type(2)));
typedef _Float16 half4_t __attribute__((ext_vector_type(4)));
typedef _Float16 f16x8 __attribute__((ext_vector_type(8)));
typedef float f32x4 __attribute__((ext_vector_type(4)));

static __device__ __forceinline__ float leaky02(float x) {
    return x > 0.f ? x : 0.2f * x;
}
static __device__ __forceinline__ float elu1(float x) {
    return x > 0.f ? x : __expf(x) - 1.f;
}

// ---------------- init counts + W1/W2 fp16 transpose (fused) ----------------

__global__ void init_prep_kernel(int* __restrict__ cnt, int n,
                                 const float* __restrict__ W1,
                                 const float* __restrict__ W2,
                                 _Float16* __restrict__ Wt1,
                                 _Float16* __restrict__ Wt2, int nInit) {
    int b = blockIdx.x;
    int t = threadIdx.x;
    if (b < nInit) {
        int i = b * 256 + t;
        if (i < n) cnt[i] = 1;  // self-loop contributes 1 incoming edge
    } else {
        int idx = (b - nInit) * 256 + t;  // 0..32767
        int which = idx >> 14;
        int r = idx & 16383;
        int nc = r >> 7, k = r & 127;
        if (which == 0)
            Wt1[(size_t)nc * 128 + k] = (_Float16)W1[(size_t)k * 128 + nc];
        else
            Wt2[(size_t)nc * 128 + k] = (_Float16)W2[(size_t)k * 128 + nc];
    }
}

// ---------------- XCD-partitioned histogram ----------------
// range = blockIdx%8 (round-robin XCD heuristic; correctness mapping-free):
// block only counts dst in its range -> cnt slice stays in one L2.

__global__ void hist_x_kernel(const int* __restrict__ dst, int* __restrict__ cnt,
                              int e, int n, int nch) {
    int b = blockIdx.x;
    int range = b & 7, chunk = b >> 3;
    int rsz = (n + 7) >> 3;
    int rlo = range * rsz;
    int rhi = min(n, rlo + rsz);
    int csz = (e + nch - 1) / nch;
    int lo = chunk * csz;
    int hi = min(e, lo + csz);
    for (int i = lo + (int)threadIdx.x; i < hi; i += 256) {
        int d = dst[i];
        if (d >= rlo && d < rhi) atomicAdd(&cnt[d], 1);
    }
}

// inclusive scan of 2048-element tiles; per-tile totals to sums[]
__global__ void scan_tile_kernel(const int* __restrict__ in, int* __restrict__ out,
                                 int* __restrict__ sums, int n) {
    __shared__ int sdata[256];
    int t = threadIdx.x;
    int base = blockIdx.x * 2048 + t * 8;
    int v[8];
    int run = 0;
#pragma unroll
    for (int i = 0; i < 8; ++i) {
        int idx = base + i;
        int x = (idx < n) ? in[idx] : 0;
        run += x;
        v[i] = run;
    }
    sdata[t] = run;
    __syncthreads();
    for (int off = 1; off < 256; off <<= 1) {
        int u = (t >= off) ? sdata[t - off] : 0;
        __syncthreads();
        sdata[t] += u;
        __syncthreads();
    }
    int excl = sdata[t] - run;
#pragma unroll
    for (int i = 0; i < 8; ++i) {
        int idx = base + i;
        if (idx < n) out[idx] = v[i] + excl;
    }
    if (t == 0) sums[blockIdx.x] = sdata[255];
}

// exclusive scan of up to 64 tile sums (single wave)
__global__ void scan_sums_kernel(int* __restrict__ sums, int nb) {
    int t = threadIdx.x;  // 64 threads
    int orig = (t < nb) ? sums[t] : 0;
    int v = orig;
#pragma unroll
    for (int off = 1; off < 64; off <<= 1) {
        int u = __shfl_up(v, off, 64);
        if (t >= off) v += u;
    }
    if (t < nb) sums[t] = v - orig;  // exclusive prefix
}

// row_ptr[i+1] = incl-scan(i); cursor[i] = row_ptr[i]
__global__ void scan_finish_kernel(const int* __restrict__ incl, const int* __restrict__ sums,
                                   int* __restrict__ row_ptr, int* __restrict__ cursor, int n) {
    int i = blockIdx.x * blockDim.x + threadIdx.x;
    if (i < n) {
        row_ptr[i + 1] = incl[i] + sums[i >> 11];
        cursor[i] = (i == 0) ? 0 : incl[i - 1] + sums[(i - 1) >> 11];
    }
    if (i == 0) row_ptr[0] = 0;
}

// ---------------- fused: MFMA gemm1 + XCD-partitioned scatter ----------------
// gemm blocks [0, nGemm) (nGemm multiple of 8 so scatter blocks keep %8 phase);
// scatter blocks: range = blockIdx%8, only edges with dst in range ->
// csr/cursor slices L2-local. chunk==0 blocks also insert self-loops.

__global__ __launch_bounds__(256) void gemm1_fused_kernel(
    const float* __restrict__ X, const _Float16* __restrict__ Wt,
    _Float16* __restrict__ H16, int nrows, const int* __restrict__ src,
    const int* __restrict__ dst, int* __restrict__ cursor, int* __restrict__ csr,
    int E, int nGemm, int nScatCh) {
    int b = blockIdx.x;
    int t = threadIdx.x;
    if (b < nGemm) {
        int wave = t >> 6, lane = t & 63;
        int m = lane & 15, q = lane >> 4;
        int arow = b * 64 + wave * 16 + m;
        bool rowok = arow < nrows;
        const float* xr = X + (size_t)arow * 128;
        f16x8 afrag[4];
#pragma unroll
        for (int s = 0; s < 4; ++s) {
            float4 v0 = make_float4(0.f, 0.f, 0.f, 0.f);
            float4 v1 = make_float4(0.f, 0.f, 0.f, 0.f);
            if (rowok) {
                v0 = *(const float4*)(xr + s * 32 + q * 8);
                v1 = *(const float4*)(xr + s * 32 + q * 8 + 4);
            }
            f16x8 a;
            a[0] = (_Float16)v0.x; a[1] = (_Float16)v0.y;
            a[2] = (_Float16)v0.z; a[3] = (_Float16)v0.w;
            a[4] = (_Float16)v1.x; a[5] = (_Float16)v1.y;
            a[6] = (_Float16)v1.z; a[7] = (_Float16)v1.w;
            afrag[s] = a;
        }
#pragma unroll
        for (int c = 0; c < 8; ++c) {
            f32x4 acc = {0.f, 0.f, 0.f, 0.f};
#pragma unroll
            for (int s = 0; s < 4; ++s) {
                f16x8 bfrag = *(const f16x8*)(Wt + (size_t)(c * 16 + m) * 128 + s * 32 + q * 8);
                acc = __builtin_amdgcn_mfma_f32_16x16x32_f16(afrag[s], bfrag, acc, 0, 0, 0);
            }
#pragma unroll
            for (int r = 0; r < 4; ++r) {
                int orow = b * 64 + wave * 16 + q * 4 + r;
                if (orow < nrows)
                    H16[(size_t)orow * 128 + c * 16 + m] = (_Float16)acc[r];
            }
        }
    } else {
        int sb = b - nGemm;
        int range = b & 7;        // nGemm % 8 == 0 -> same as sb & 7
        int chunk = sb >> 3;
        int rsz = (nrows + 7) >> 3;
        int rlo = range * rsz;
        int rhi = min(nrows, rlo + rsz);
        int csz = (E + nScatCh - 1) / nScatCh;
        int lo = chunk * csz;
        int hi = min(E, lo + csz);
        for (int i = lo + t; i < hi; i += 256) {
            int d = dst[i];
            if (d >= rlo && d < rhi) {
                int p = atomicAdd(&cursor[d], 1);
                csr[p] = src[i];
            }
        }
        if (chunk == 0) {
            for (int i = rlo + t; i < rhi; i += 256) {
                int p = atomicAdd(&cursor[i], 1);
                csr[p] = i;
            }
        }
    }
}

// ---------------- MFMA gemm2 (fp16 A) ----------------
__global__ __launch_bounds__(256) void gemm2_mfma_kernel(
    const _Float16* __restrict__ A16, const _Float16* __restrict__ Wt,
    _Float16* __restrict__ H16, int nrows) {
    int b = blockIdx.x;
    int t = threadIdx.x;
    int wave = t >> 6, lane = t & 63;
    int m = lane & 15, q = lane >> 4;
    int arow = b * 64 + wave * 16 + m;
    bool rowok = arow < nrows;
    const _Float16* ar = A16 + (size_t)arow * 128;
    f16x8 afrag[4];
#pragma unroll
    for (int s = 0; s < 4; ++s) {
        f16x8 a = {};
        if (rowok) a = *(const f16x8*)(ar + s * 32 + q * 8);
        afrag[s] = a;
    }
#pragma unroll
    for (int c = 0; c < 8; ++c) {
        f32x4 acc = {0.f, 0.f, 0.f, 0.f};
#pragma unroll
        for (int s = 0; s < 4; ++s) {
            f16x8 bfrag = *(const f16x8*)(Wt + (size_t)(c * 16 + m) * 128 + s * 32 + q * 8);
            acc = __builtin_amdgcn_mfma_f32_16x16x32_f16(afrag[s], bfrag, acc, 0, 0, 0);
        }
#pragma unroll
        for (int r = 0; r < 4; ++r) {
            int orow = b * 64 + wave * 16 + q * 4 + r;
            if (orow < nrows)
                H16[(size_t)orow * 128 + c * 16 + m] = (_Float16)acc[r];
        }
    }
}

// ---------------- attention halves (read fp16 features) ----------------
__global__ void alpha1_kernel(const _Float16* __restrict__ H16, const float* __restrict__ a_src,
                              const float* __restrict__ a_dst, float* __restrict__ asrc_out,
                              float* __restrict__ adst_out, int n) {
    int wave = (blockIdx.x * blockDim.x + threadIdx.x) >> 6;
    int lane = threadIdx.x & 63;
    if (wave >= n) return;
    int c = lane * 2;
    half2_t hv = *(const half2_t*)(H16 + (size_t)wave * 128 + c);
    float2 as = *(const float2*)(a_src + c);
    float2 ad = *(const float2*)(a_dst + c);
    float hx = (float)hv.x, hy = (float)hv.y;
    float ps = hx * as.x + hy * as.y;
    float pd = hx * ad.x + hy * ad.y;
#pragma unroll
    for (int off = 1; off <= 8; off <<= 1) {
        ps += __shfl_xor(ps, off, 64);
        pd += __shfl_xor(pd, off, 64);
    }
    if ((lane & 15) == 0) {
        int h = lane >> 4;
        asrc_out[wave * 4 + h] = ps;
        adst_out[wave * 4 + h] = pd;
    }
}

__global__ void alpha2_kernel(const _Float16* __restrict__ H16, const float* __restrict__ a_src,
                              const float* __restrict__ a_dst, float* __restrict__ asrc_out,
                              float* __restrict__ adst_out, int n) {
    int wave = (blockIdx.x * blockDim.x + threadIdx.x) >> 6;
    int lane = threadIdx.x & 63;
    if (wave >= n) return;
    int c = lane * 2;
    half2_t hv = *(const half2_t*)(H16 + (size_t)wave * 128 + c);
    float2 as = *(const float2*)(a_src + c);
    float2 ad = *(const float2*)(a_dst + c);
    float hx = (float)hv.x, hy = (float)hv.y;
    float ps = hx * as.x + hy * as.y;
    float pd = hx * ad.x + hy * ad.y;
#pragma unroll
    for (int off = 1; off <= 32; off <<= 1) {
        ps += __shfl_xor(ps, off, 64);
        pd += __shfl_xor(pd, off, 64);
    }
    if (lane == 0) {
        asrc_out[wave] = ps;
        adst_out[wave] = pd;
    }
}

// ---------------- softmax aggregation ----------------
// 2 nodes/wave: lanes 0-31 -> node 2w, lanes 32-63 -> node 2w+1.
// lane owns 4 channels (one 8B half4 gather per edge).

__global__ __launch_bounds__(256) void agg1_kernel(
    const _Float16* __restrict__ H16, const float* __restrict__ asrc,
    const float* __restrict__ adst, const int* __restrict__ row_ptr,
    const int* __restrict__ csr, const float* __restrict__ bias,
    _Float16* __restrict__ out16, int n) {
    int wid = (blockIdx.x * blockDim.x + threadIdx.x) >> 6;
    int lane = threadIdx.x & 63;
    int node = wid * 2 + (lane >> 5);
    if (node >= n) return;
    int sub = lane & 31;
    int c = sub * 4;
    int h = sub >> 3;  // head = c >> 5
    float adh = adst[node * 4 + h];
    float4 bv = *(const float4*)(bias + c);
    int e0 = row_ptr[node];
    int e1 = row_ptr[node + 1];
    float den = 0.f, a0 = 0.f, a1 = 0.f, a2 = 0.f, a3 = 0.f;
    int e = e0;
    for (; e + 4 <= e1; e += 4) {
        int s0 = csr[e + 0], s1 = csr[e + 1], s2 = csr[e + 2], s3 = csr[e + 3];
        float l0 = asrc[s0 * 4 + h];
        float l1 = asrc[s1 * 4 + h];
        float l2 = asrc[s2 * 4 + h];
        float l3 = asrc[s3 * 4 + h];
        half4_t g0 = *(const half4_t*)(H16 + (size_t)s0 * 128 + c);
        half4_t g1 = *(const half4_t*)(H16 + (size_t)s1 * 128 + c);
        half4_t g2 = *(const half4_t*)(H16 + (size_t)s2 * 128 + c);
        half4_t g3 = *(const half4_t*)(H16 + (size_t)s3 * 128 + c);
        float w0 = __expf(leaky02(l0 + adh));
        float w1 = __expf(leaky02(l1 + adh));
        float w2 = __expf(leaky02(l2 + adh));
        float w3 = __expf(leaky02(l3 + adh));
        den += (w0 + w1) + (w2 + w3);
        a0 += w0 * (float)g0.x + w1 * (float)g1.x + w2 * (float)g2.x + w3 * (float)g3.x;
        a1 += w0 * (float)g0.y + w1 * (float)g1.y + w2 * (float)g2.y + w3 * (float)g3.y;
        a2 += w0 * (float)g0.z + w1 * (float)g1.z + w2 * (float)g2.z + w3 * (float)g3.z;
        a3 += w0 * (float)g0.w + w1 * (float)g1.w + w2 * (float)g2.w + w3 * (float)g3.w;
    }
    for (; e < e1; ++e) {
        int s = csr[e];
        float w = __expf(leaky02(asrc[s * 4 + h] + adh));
        half4_t g = *(const half4_t*)(H16 + (size_t)s * 128 + c);
        den += w;
        a0 += w * (float)g.x;
        a1 += w * (float)g.y;
        a2 += w * (float)g.z;
        a3 += w * (float)g.w;
    }
    float inv = 1.f / (den + 1e-16f);
    half4_t o;
    o.x = (_Float16)elu1(a0 * inv + bv.x);
    o.y = (_Float16)elu1(a1 * inv + bv.y);
    o.z = (_Float16)elu1(a2 * inv + bv.z);
    o.w = (_Float16)elu1(a3 * inv + bv.w);
    *(half4_t*)(out16 + (size_t)node * 128 + c) = o;
}

__global__ __launch_bounds__(256) void agg2_kernel(
    const _Float16* __restrict__ H16, const float* __restrict__ asrc,
    const float* __restrict__ adst, const int* __restrict__ row_ptr,
    const int* __restrict__ csr, const float* __restrict__ bias,
    float* __restrict__ out, int n) {
    int wid = (blockIdx.x * blockDim.x + threadIdx.x) >> 6;
    int lane = threadIdx.x & 63;
    int node = wid * 2 + (lane >> 5);
    if (node >= n) return;
    int sub = lane & 31;
    int c = sub * 4;
    float adh = adst[node];
    float4 bv = *(const float4*)(bias + c);
    int e0 = row_ptr[node];
    int e1 = row_ptr[node + 1];
    float den = 0.f, a0 = 0.f, a1 = 0.f, a2 = 0.f, a3 = 0.f;
    int e = e0;
    for (; e + 4 <= e1; e += 4) {
        int s0 = csr[e + 0], s1 = csr[e + 1], s2 = csr[e + 2], s3 = csr[e + 3];
        float l0 = asrc[s0];
        float l1 = asrc[s1];
        float l2 = asrc[s2];
        float l3 = asrc[s3];
        half4_t g0 = *(const half4_t*)(H16 + (size_t)s0 * 128 + c);
        half4_t g1 = *(const half4_t*)(H16 + (size_t)s1 * 128 + c);
        half4_t g2 = *(const half4_t*)(H16 + (size_t)s2 * 128 + c);
        half4_t g3 = *(const half4_t*)(H16 + (size_t)s3 * 128 + c);
        float w0 = __expf(leaky02(l0 + adh));
        float w1 = __expf(leaky02(l1 + adh));
        float w2 = __expf(leaky02(l2 + adh));
        float w3 = __expf(leaky02(l3 + adh));
        den += (w0 + w1) + (w2 + w3);
        a0 += w0 * (float)g0.x + w1 * (float)g1.x + w2 * (float)g2.x + w3 * (float)g3.x;
        a1 += w0 * (float)g0.y + w1 * (float)g1.y + w2 * (float)g2.y + w3 * (float)g3.y;
        a2 += w0 * (float)g0.z + w1 * (float)g1.z + w2 * (float)g2.z + w3 * (float)g3.z;
        a3 += w0 * (float)g0.w + w1 * (float)g1.w + w2 * (float)g2.w + w3 * (float)g3.w;
    }
    for (; e < e1; ++e) {
        int s = csr[e];
        float w = __expf(leaky02(asrc[s] + adh));
        half4_t g = *(const half4_t*)(H16 + (size_t)s * 128 + c);
        den += w;
        a0 += w * (float)g.x;
        a1 += w * (float)g.y;
        a2 += w * (float)g.z;
        a3 += w * (float)g.w;
    }
    float inv = 1.f / (den + 1e-16f);
    float4 o;
    o.x = elu1(a0 * inv + bv.x);
    o.y = elu1(a1 * inv + bv.y);
    o.z = elu1(a2 * inv + bv.z);
    o.w = elu1(a3 * inv + bv.w);
    *(float4*)(out + (size_t)node * 128 + c) = o;
}

// ---------------- host ----------------

extern "C" void kernel_launch(void* const* d_in, const int* in_sizes, int n_in,
                              void* d_out, int out_size, void* d_ws, size_t ws_size,
                              hipStream_t stream) {
    const float* x       = (const float*)d_in[0];
    const int*   eidx    = (const int*)d_in[1];
    const float* W1      = (const float*)d_in[2];
    const float* a_src1  = (const float*)d_in[3];
    const float* a_dst1  = (const float*)d_in[4];
    const float* b1      = (const float*)d_in[5];
    const float* W2      = (const float*)d_in[6];
    const float* a_src2  = (const float*)d_in[7];
    const float* a_dst2  = (const float*)d_in[8];
    const float* b2      = (const float*)d_in[9];
    float* out = (float*)d_out;

    const int N = in_sizes[0] / 128;  // 50000
    const int E = in_sizes[1] / 2;    // 800000
    const int* src = eidx;
    const int* dst = eidx + E;

    // workspace carve-up (~29 MB)
    char* w = (char*)d_ws;
    _Float16* bufH16 = (_Float16*)w; w += (size_t)N * 128 * sizeof(_Float16);
    _Float16* bufA16 = (_Float16*)w; w += (size_t)N * 128 * sizeof(_Float16);
    _Float16* Wt1    = (_Float16*)w; w += (size_t)128 * 128 * sizeof(_Float16);
    _Float16* Wt2    = (_Float16*)w; w += (size_t)128 * 128 * sizeof(_Float16);
    float* asrc = (float*)w;   w += (size_t)N * 4 * sizeof(float);
    float* adst = (float*)w;   w += (size_t)N * 4 * sizeof(float);
    int* cnt     = (int*)w;    w += (size_t)N * sizeof(int);
    int* incl    = (int*)w;    w += (size_t)N * sizeof(int);
    int* row_ptr = (int*)w;    w += (size_t)(N + 1) * sizeof(int);
    int* cursor  = (int*)w;    w += (size_t)N * sizeof(int);
    int* sums    = (int*)w;    w += 64 * sizeof(int);
    int* csr     = (int*)w;    w += (size_t)(E + N) * sizeof(int);

    const int ntiles = (N + 2047) / 2048;  // 25
    dim3 b256(256);
    dim3 gN((N + 255) / 256);
    dim3 gWave((N + 3) / 4);                     // 1 node/wave kernels
    dim3 gAgg(((((N + 1) / 2) + 3) / 4));        // 2 nodes/wave kernels
    const int nGemm = (((N + 63) / 64) + 7) & ~7;  // 784, multiple of 8
    const int nInit = (N + 255) / 256;           // 196
    const int histCh = 200;                      // 8*200 = 1600 blocks
    const int scatCh = 96;                       // 8*96 = 768 scatter blocks

    // ---- CSR prefix chain + weight prep ----
    hipLaunchKernelGGL(init_prep_kernel, dim3(nInit + 128), b256, 0, stream, cnt, N, W1, W2,
                       Wt1, Wt2, nInit);
    hipLaunchKernelGGL(hist_x_kernel, dim3(8 * histCh), b256, 0, stream, dst, cnt, E, N, histCh);
    hipLaunchKernelGGL(scan_tile_kernel, dim3(ntiles), b256, 0, stream, cnt, incl, sums, N);
    hipLaunchKernelGGL(scan_sums_kernel, dim3(1), dim3(64), 0, stream, sums, ntiles);
    hipLaunchKernelGGL(scan_finish_kernel, gN, b256, 0, stream, incl, sums, row_ptr, cursor, N);

    // ---- layer 1: gemm1 + XCD-partitioned scatter fused ----
    hipLaunchKernelGGL(gemm1_fused_kernel, dim3(nGemm + 8 * scatCh), b256, 0, stream, x, Wt1,
                       bufH16, N, src, dst, cursor, csr, E, nGemm, scatCh);
    hipLaunchKernelGGL(alpha1_kernel, gWave, b256, 0, stream, bufH16, a_src1, a_dst1, asrc, adst, N);
    hipLaunchKernelGGL(agg1_kernel, gAgg, b256, 0, stream, bufH16, asrc, adst, row_ptr, csr, b1,
                       bufA16, N);

    // ---- layer 2 ----
    hipLaunchKernelGGL(gemm2_mfma_kernel, dim3((N + 63) / 64), b256, 0, stream, bufA16, Wt2,
                       bufH16, N);
    hipLaunchKernelGGL(alpha2_kernel, gWave, b256, 0, stream, bufH16, a_src2, a_dst2, asrc, adst, N);
    hipLaunchKernelGGL(agg2_kernel, gAgg, b256, 0, stream, bufH16, asrc, adst, row_ptr, csr, b2,
                       out, N);
}

// Round 5
// 247.295 us; speedup vs baseline: 1.8048x; 1.1999x over previous
//
#include <hip/hip_runtime.h>
#include <hip/hip_bf16.h>

// ---------------------------------------------------------------------------
// SimplifiedGATBlock: 2-layer GAT, N=50000, E=800000 (+self loops)
// R5: global-atomic scatter (R2-R4: ~50-60us invariant) replaced by a
// deterministic two-level bucket sort with LDS-only atomics:
//   prep(hist 196 buckets x 128 blocks) -> scan -> binscatter (pre-scanned
//   disjoint ranges, coalesced) -> per-bucket LDS counting sort (emits csr +
//   row_ptr, self-loops at slot 0). agg: 8-wide unroll. h1 scratch = d_out.
// ---------------------------------------------------------------------------

typedef _Float16 half2_t __attribute__((ext_vector_type(2)));
typedef _Float16 half4_t __attribute__((ext_vector_type(4)));
typedef _Float16 f16x8 __attribute__((ext_vector_type(8)));
typedef float f32x4 __attribute__((ext_vector_type(4)));

#define NBLK1 128      // edge chunks for binning
#define SORT_CAP 6144  // per-bucket LDS sort capacity (avg ~4340, 13+ sigma)

static __device__ __forceinline__ float leaky02(float x) {
    return x > 0.f ? x : 0.2f * x;
}
static __device__ __forceinline__ float elu1(float x) {
    return x > 0.f ? x : __expf(x) - 1.f;
}

// ---------------- prep: bucket histogram + W1/W2 fp16 transpose ------------
// blocks [0,NBLK1): LDS histogram of edge chunk into nbkt buckets (dst>>8).
// blocks [NBLK1, NBLK1+128): Wt transpose.

__global__ __launch_bounds__(256) void prep_kernel(
    const int* __restrict__ dst, int* __restrict__ g_cnt, int E, int chunk,
    const float* __restrict__ W1, const float* __restrict__ W2,
    _Float16* __restrict__ Wt1, _Float16* __restrict__ Wt2, int nbkt) {
    int b = blockIdx.x;
    int t = threadIdx.x;
    if (b < NBLK1) {
        __shared__ int h[256];
        h[t] = 0;
        __syncthreads();
        int lo = b * chunk, hi = min(E, lo + chunk);
        for (int i = lo + t; i < hi; i += 256) atomicAdd(&h[dst[i] >> 8], 1);
        __syncthreads();
        if (t < nbkt) g_cnt[t * NBLK1 + b] = h[t];
    } else {
        int idx = (b - NBLK1) * 256 + t;  // 0..32767
        int which = idx >> 14;
        int r = idx & 16383;
        int nc = r >> 7, k = r & 127;
        if (which == 0)
            Wt1[(size_t)nc * 128 + k] = (_Float16)W1[(size_t)k * 128 + nc];
        else
            Wt2[(size_t)nc * 128 + k] = (_Float16)W2[(size_t)k * 128 + nc];
    }
}

// inclusive scan of 2048-element tiles; per-tile totals to sums[]
__global__ void scan_tile_kernel(const int* __restrict__ in, int* __restrict__ out,
                                 int* __restrict__ sums, int n) {
    __shared__ int sdata[256];
    int t = threadIdx.x;
    int base = blockIdx.x * 2048 + t * 8;
    int v[8];
    int run = 0;
#pragma unroll
    for (int i = 0; i < 8; ++i) {
        int idx = base + i;
        int x = (idx < n) ? in[idx] : 0;
        run += x;
        v[i] = run;
    }
    sdata[t] = run;
    __syncthreads();
    for (int off = 1; off < 256; off <<= 1) {
        int u = (t >= off) ? sdata[t - off] : 0;
        __syncthreads();
        sdata[t] += u;
        __syncthreads();
    }
    int excl = sdata[t] - run;
#pragma unroll
    for (int i = 0; i < 8; ++i) {
        int idx = base + i;
        if (idx < n) out[idx] = v[i] + excl;
    }
    if (t == 0) sums[blockIdx.x] = sdata[255];
}

// exclusive scan of up to 64 tile sums (single wave)
__global__ void scan_sums_kernel(int* __restrict__ sums, int nb) {
    int t = threadIdx.x;  // 64 threads
    int orig = (t < nb) ? sums[t] : 0;
    int v = orig;
#pragma unroll
    for (int off = 1; off < 64; off <<= 1) {
        int u = __shfl_up(v, off, 64);
        if (t >= off) v += u;
    }
    if (t < nb) sums[t] = v - orig;  // exclusive prefix
}

// offs[i] = exclusive prefix over g_cnt, i in [0, ncnt]
__global__ void offs_kernel(const int* __restrict__ incl, const int* __restrict__ sums,
                            int* __restrict__ offs, int ncnt) {
    int i = blockIdx.x * blockDim.x + threadIdx.x;
    if (i <= ncnt) offs[i] = (i == 0) ? 0 : incl[i - 1] + sums[(i - 1) >> 11];
}

// ---------------- fused: MFMA gemm1 + bin scatter (no global atomics) ------

__global__ __launch_bounds__(256) void gemm1_fused_kernel(
    const float* __restrict__ X, const _Float16* __restrict__ Wt,
    _Float16* __restrict__ H16, int nrows, const int* __restrict__ src,
    const int* __restrict__ dst, const int* __restrict__ offs,
    int2* __restrict__ binned, int E, int chunk, int nGemm, int nbkt) {
    int b = blockIdx.x;
    int t = threadIdx.x;
    if (b < nGemm) {
        int wave = t >> 6, lane = t & 63;
        int m = lane & 15, q = lane >> 4;
        int arow = b * 64 + wave * 16 + m;
        bool rowok = arow < nrows;
        const float* xr = X + (size_t)arow * 128;
        f16x8 afrag[4];
#pragma unroll
        for (int s = 0; s < 4; ++s) {
            float4 v0 = make_float4(0.f, 0.f, 0.f, 0.f);
            float4 v1 = make_float4(0.f, 0.f, 0.f, 0.f);
            if (rowok) {
                v0 = *(const float4*)(xr + s * 32 + q * 8);
                v1 = *(const float4*)(xr + s * 32 + q * 8 + 4);
            }
            f16x8 a;
            a[0] = (_Float16)v0.x; a[1] = (_Float16)v0.y;
            a[2] = (_Float16)v0.z; a[3] = (_Float16)v0.w;
            a[4] = (_Float16)v1.x; a[5] = (_Float16)v1.y;
            a[6] = (_Float16)v1.z; a[7] = (_Float16)v1.w;
            afrag[s] = a;
        }
#pragma unroll
        for (int c = 0; c < 8; ++c) {
            f32x4 acc = {0.f, 0.f, 0.f, 0.f};
#pragma unroll
            for (int s = 0; s < 4; ++s) {
                f16x8 bfrag = *(const f16x8*)(Wt + (size_t)(c * 16 + m) * 128 + s * 32 + q * 8);
                acc = __builtin_amdgcn_mfma_f32_16x16x32_f16(afrag[s], bfrag, acc, 0, 0, 0);
            }
#pragma unroll
            for (int r = 0; r < 4; ++r) {
                int orow = b * 64 + wave * 16 + q * 4 + r;
                if (orow < nrows)
                    H16[(size_t)orow * 128 + c * 16 + m] = (_Float16)acc[r];
            }
        }
    } else {
        __shared__ int cur[256];
        int sb = b - nGemm;  // 0..NBLK1-1
        if (t < nbkt) cur[t] = offs[t * NBLK1 + sb];
        __syncthreads();
        int lo = sb * chunk, hi = min(E, lo + chunk);
        for (int i = lo + t; i < hi; i += 256) {
            int d = dst[i];
            int s = src[i];
            int p = atomicAdd(&cur[d >> 8], 1);  // LDS atomic: disjoint global range
            binned[p] = make_int2(s, d);
        }
    }
}

// ---------------- fused: per-bucket LDS counting sort + alpha1 -------------
// blocks [0,nbkt): sort bucket b (256 nodes), emit csr + row_ptr, self at
// slot 0. blocks [nbkt, ...): alpha1 (wave per node).

__global__ __launch_bounds__(256) void sort_alpha1_kernel(
    const int2* __restrict__ binned, const int* __restrict__ offs,
    int* __restrict__ row_ptr, int* __restrict__ csr, int n, int nbkt,
    const _Float16* __restrict__ H16, const float* __restrict__ a_src,
    const float* __restrict__ a_dst, float* __restrict__ asrc_out,
    float* __restrict__ adst_out) {
    int b = blockIdx.x;
    int t = threadIdx.x;
    if (b < nbkt) {
        __shared__ int sorted[SORT_CAP];
        __shared__ int sdata[256];
        __shared__ int cur[256];
        int estart = offs[b * NBLK1];
        int eend = offs[(b + 1) * NBLK1];
        int node0 = b * 256;
        int nloc = min(256, n - node0);
        int cnt0 = (t < nloc) ? 1 : 0;  // self-loop seed
        cur[t] = cnt0;
        __syncthreads();
        for (int i = estart + t; i < eend; i += 256)
            atomicAdd(&cur[binned[i].y & 255], 1);
        __syncthreads();
        int my = cur[t];
        sdata[t] = my;
        __syncthreads();
        for (int off = 1; off < 256; off <<= 1) {
            int u = (t >= off) ? sdata[t - off] : 0;
            __syncthreads();
            sdata[t] += u;
            __syncthreads();
        }
        int excl = sdata[t] - my;
        int total = sdata[255];
        int csr_base = estart + node0;  // earlier buckets are full: +256 selfs each
        if (node0 + t <= n) row_ptr[node0 + t] = csr_base + excl;
        if (t == 0 && node0 + 256 <= n) row_ptr[node0 + 256] = csr_base + total;
        if (t < nloc) {
            if (excl < SORT_CAP) sorted[excl] = node0 + t;  // self loop
            else csr[csr_base + excl] = node0 + t;
            cur[t] = excl + 1;
        } else {
            cur[t] = 0;
        }
        __syncthreads();
        for (int i = estart + t; i < eend; i += 256) {
            int2 pr = binned[i];
            int p = atomicAdd(&cur[pr.y & 255], 1);
            if (p < SORT_CAP) sorted[p] = pr.x;
            else csr[csr_base + p] = pr.x;  // overflow fallback (near-impossible)
        }
        __syncthreads();
        int lim = min(total, SORT_CAP);
        for (int j = t; j < lim; j += 256) csr[csr_base + j] = sorted[j];
    } else {
        int node = (b - nbkt) * 4 + (t >> 6);
        int lane = t & 63;
        if (node >= n) return;
        int c = lane * 2;
        half2_t hv = *(const half2_t*)(H16 + (size_t)node * 128 + c);
        float2 as = *(const float2*)(a_src + c);
        float2 ad = *(const float2*)(a_dst + c);
        float hx = (float)hv.x, hy = (float)hv.y;
        float ps = hx * as.x + hy * as.y;
        float pd = hx * ad.x + hy * ad.y;
#pragma unroll
        for (int off = 1; off <= 8; off <<= 1) {
            ps += __shfl_xor(ps, off, 64);
            pd += __shfl_xor(pd, off, 64);
        }
        if ((lane & 15) == 0) {
            int h = lane >> 4;
            asrc_out[node * 4 + h] = ps;
            adst_out[node * 4 + h] = pd;
        }
    }
}

// ---------------- MFMA gemm2 (fp16 A) ----------------
__global__ __launch_bounds__(256) void gemm2_mfma_kernel(
    const _Float16* __restrict__ A16, const _Float16* __restrict__ Wt,
    _Float16* __restrict__ H16, int nrows) {
    int b = blockIdx.x;
    int t = threadIdx.x;
    int wave = t >> 6, lane = t & 63;
    int m = lane & 15, q = lane >> 4;
    int arow = b * 64 + wave * 16 + m;
    bool rowok = arow < nrows;
    const _Float16* ar = A16 + (size_t)arow * 128;
    f16x8 afrag[4];
#pragma unroll
    for (int s = 0; s < 4; ++s) {
        f16x8 a = {};
        if (rowok) a = *(const f16x8*)(ar + s * 32 + q * 8);
        afrag[s] = a;
    }
#pragma unroll
    for (int c = 0; c < 8; ++c) {
        f32x4 acc = {0.f, 0.f, 0.f, 0.f};
#pragma unroll
        for (int s = 0; s < 4; ++s) {
            f16x8 bfrag = *(const f16x8*)(Wt + (size_t)(c * 16 + m) * 128 + s * 32 + q * 8);
            acc = __builtin_amdgcn_mfma_f32_16x16x32_f16(afrag[s], bfrag, acc, 0, 0, 0);
        }
#pragma unroll
        for (int r = 0; r < 4; ++r) {
            int orow = b * 64 + wave * 16 + q * 4 + r;
            if (orow < nrows)
                H16[(size_t)orow * 128 + c * 16 + m] = (_Float16)acc[r];
        }
    }
}

__global__ void alpha2_kernel(const _Float16* __restrict__ H16, const float* __restrict__ a_src,
                              const float* __restrict__ a_dst, float* __restrict__ asrc_out,
                              float* __restrict__ adst_out, int n) {
    int wave = (blockIdx.x * blockDim.x + threadIdx.x) >> 6;
    int lane = threadIdx.x & 63;
    if (wave >= n) return;
    int c = lane * 2;
    half2_t hv = *(const half2_t*)(H16 + (size_t)wave * 128 + c);
    float2 as = *(const float2*)(a_src + c);
    float2 ad = *(const float2*)(a_dst + c);
    float hx = (float)hv.x, hy = (float)hv.y;
    float ps = hx * as.x + hy * as.y;
    float pd = hx * ad.x + hy * ad.y;
#pragma unroll
    for (int off = 1; off <= 32; off <<= 1) {
        ps += __shfl_xor(ps, off, 64);
        pd += __shfl_xor(pd, off, 64);
    }
    if (lane == 0) {
        asrc_out[wave] = ps;
        adst_out[wave] = pd;
    }
}

// ---------------- softmax aggregation ----------------
// 2 nodes/wave, lane owns 4 channels, 8-wide edge unroll.

__global__ __launch_bounds__(256) void agg1_kernel(
    const _Float16* __restrict__ H16, const float* __restrict__ asrc,
    const float* __restrict__ adst, const int* __restrict__ row_ptr,
    const int* __restrict__ csr, const float* __restrict__ bias,
    _Float16* __restrict__ out16, int n) {
    int wid = (blockIdx.x * blockDim.x + threadIdx.x) >> 6;
    int lane = threadIdx.x & 63;
    int node = wid * 2 + (lane >> 5);
    if (node >= n) return;
    int sub = lane & 31;
    int c = sub * 4;
    int h = sub >> 3;
    float adh = adst[node * 4 + h];
    float4 bv = *(const float4*)(bias + c);
    int e0 = row_ptr[node];
    int e1 = row_ptr[node + 1];
    float den = 0.f, a0 = 0.f, a1 = 0.f, a2 = 0.f, a3 = 0.f;
    int e = e0;
    for (; e + 8 <= e1; e += 8) {
        int s[8];
#pragma unroll
        for (int j = 0; j < 8; ++j) s[j] = csr[e + j];
        float l[8];
        half4_t g[8];
#pragma unroll
        for (int j = 0; j < 8; ++j) {
            l[j] = asrc[s[j] * 4 + h];
            g[j] = *(const half4_t*)(H16 + (size_t)s[j] * 128 + c);
        }
#pragma unroll
        for (int j = 0; j < 8; ++j) {
            float w = __expf(leaky02(l[j] + adh));
            den += w;
            a0 += w * (float)g[j].x;
            a1 += w * (float)g[j].y;
            a2 += w * (float)g[j].z;
            a3 += w * (float)g[j].w;
        }
    }
    for (; e + 4 <= e1; e += 4) {
        int s0 = csr[e + 0], s1 = csr[e + 1], s2 = csr[e + 2], s3 = csr[e + 3];
        float l0 = asrc[s0 * 4 + h], l1 = asrc[s1 * 4 + h];
        float l2 = asrc[s2 * 4 + h], l3 = asrc[s3 * 4 + h];
        half4_t g0 = *(const half4_t*)(H16 + (size_t)s0 * 128 + c);
        half4_t g1 = *(const half4_t*)(H16 + (size_t)s1 * 128 + c);
        half4_t g2 = *(const half4_t*)(H16 + (size_t)s2 * 128 + c);
        half4_t g3 = *(const half4_t*)(H16 + (size_t)s3 * 128 + c);
        float w0 = __expf(leaky02(l0 + adh));
        float w1 = __expf(leaky02(l1 + adh));
        float w2 = __expf(leaky02(l2 + adh));
        float w3 = __expf(leaky02(l3 + adh));
        den += (w0 + w1) + (w2 + w3);
        a0 += w0 * (float)g0.x + w1 * (float)g1.x + w2 * (float)g2.x + w3 * (float)g3.x;
        a1 += w0 * (float)g0.y + w1 * (float)g1.y + w2 * (float)g2.y + w3 * (float)g3.y;
        a2 += w0 * (float)g0.z + w1 * (float)g1.z + w2 * (float)g2.z + w3 * (float)g3.z;
        a3 += w0 * (float)g0.w + w1 * (float)g1.w + w2 * (float)g2.w + w3 * (float)g3.w;
    }
    for (; e < e1; ++e) {
        int s = csr[e];
        float w = __expf(leaky02(asrc[s * 4 + h] + adh));
        half4_t g = *(const half4_t*)(H16 + (size_t)s * 128 + c);
        den += w;
        a0 += w * (float)g.x;
        a1 += w * (float)g.y;
        a2 += w * (float)g.z;
        a3 += w * (float)g.w;
    }
    float inv = 1.f / (den + 1e-16f);
    half4_t o;
    o.x = (_Float16)elu1(a0 * inv + bv.x);
    o.y = (_Float16)elu1(a1 * inv + bv.y);
    o.z = (_Float16)elu1(a2 * inv + bv.z);
    o.w = (_Float16)elu1(a3 * inv + bv.w);
    *(half4_t*)(out16 + (size_t)node * 128 + c) = o;
}

__global__ __launch_bounds__(256) void agg2_kernel(
    const _Float16* __restrict__ H16, const float* __restrict__ asrc,
    const float* __restrict__ adst, const int* __restrict__ row_ptr,
    const int* __restrict__ csr, const float* __restrict__ bias,
    float* __restrict__ out, int n) {
    int wid = (blockIdx.x * blockDim.x + threadIdx.x) >> 6;
    int lane = threadIdx.x & 63;
    int node = wid * 2 + (lane >> 5);
    if (node >= n) return;
    int sub = lane & 31;
    int c = sub * 4;
    float adh = adst[node];
    float4 bv = *(const float4*)(bias + c);
    int e0 = row_ptr[node];
    int e1 = row_ptr[node + 1];
    float den = 0.f, a0 = 0.f, a1 = 0.f, a2 = 0.f, a3 = 0.f;
    int e = e0;
    for (; e + 8 <= e1; e += 8) {
        int s[8];
#pragma unroll
        for (int j = 0; j < 8; ++j) s[j] = csr[e + j];
        float l[8];
        half4_t g[8];
#pragma unroll
        for (int j = 0; j < 8; ++j) {
            l[j] = asrc[s[j]];
            g[j] = *(const half4_t*)(H16 + (size_t)s[j] * 128 + c);
        }
#pragma unroll
        for (int j = 0; j < 8; ++j) {
            float w = __expf(leaky02(l[j] + adh));
            den += w;
            a0 += w * (float)g[j].x;
            a1 += w * (float)g[j].y;
            a2 += w * (float)g[j].z;
            a3 += w * (float)g[j].w;
        }
    }
    for (; e + 4 <= e1; e += 4) {
        int s0 = csr[e + 0], s1 = csr[e + 1], s2 = csr[e + 2], s3 = csr[e + 3];
        float l0 = asrc[s0], l1 = asrc[s1], l2 = asrc[s2], l3 = asrc[s3];
        half4_t g0 = *(const half4_t*)(H16 + (size_t)s0 * 128 + c);
        half4_t g1 = *(const half4_t*)(H16 + (size_t)s1 * 128 + c);
        half4_t g2 = *(const half4_t*)(H16 + (size_t)s2 * 128 + c);
        half4_t g3 = *(const half4_t*)(H16 + (size_t)s3 * 128 + c);
        float w0 = __expf(leaky02(l0 + adh));
        float w1 = __expf(leaky02(l1 + adh));
        float w2 = __expf(leaky02(l2 + adh));
        float w3 = __expf(leaky02(l3 + adh));
        den += (w0 + w1) + (w2 + w3);
        a0 += w0 * (float)g0.x + w1 * (float)g1.x + w2 * (float)g2.x + w3 * (float)g3.x;
        a1 += w0 * (float)g0.y + w1 * (float)g1.y + w2 * (float)g2.y + w3 * (float)g3.y;
        a2 += w0 * (float)g0.z + w1 * (float)g1.z + w2 * (float)g2.z + w3 * (float)g3.z;
        a3 += w0 * (float)g0.w + w1 * (float)g1.w + w2 * (float)g2.w + w3 * (float)g3.w;
    }
    for (; e < e1; ++e) {
        int s = csr[e];
        float w = __expf(leaky02(asrc[s] + adh));
        half4_t g = *(const half4_t*)(H16 + (size_t)s * 128 + c);
        den += w;
        a0 += w * (float)g.x;
        a1 += w * (float)g.y;
        a2 += w * (float)g.z;
        a3 += w * (float)g.w;
    }
    float inv = 1.f / (den + 1e-16f);
    float4 o;
    o.x = elu1(a0 * inv + bv.x);
    o.y = elu1(a1 * inv + bv.y);
    o.z = elu1(a2 * inv + bv.z);
    o.w = elu1(a3 * inv + bv.w);
    *(float4*)(out + (size_t)node * 128 + c) = o;
}

// ---------------- host ----------------

extern "C" void kernel_launch(void* const* d_in, const int* in_sizes, int n_in,
                              void* d_out, int out_size, void* d_ws, size_t ws_size,
                              hipStream_t stream) {
    const float* x       = (const float*)d_in[0];
    const int*   eidx    = (const int*)d_in[1];
    const float* W1      = (const float*)d_in[2];
    const float* a_src1  = (const float*)d_in[3];
    const float* a_dst1  = (const float*)d_in[4];
    const float* b1      = (const float*)d_in[5];
    const float* W2      = (const float*)d_in[6];
    const float* a_src2  = (const float*)d_in[7];
    const float* a_dst2  = (const float*)d_in[8];
    const float* b2      = (const float*)d_in[9];
    float* out = (float*)d_out;

    const int N = in_sizes[0] / 128;  // 50000
    const int E = in_sizes[1] / 2;    // 800000
    const int* src = eidx;
    const int* dst = eidx + E;

    const int nbkt = (N + 255) >> 8;          // 196 buckets of 256 nodes
    const int ncnt = nbkt * NBLK1;            // 25088
    const int chunk = (E + NBLK1 - 1) / NBLK1;  // 6250
    const int ntiles = (ncnt + 2047) / 2048;  // 13

    // workspace carve-up (~24.7 MB); fp16 h1 scratch lives in d_out.
    char* w = (char*)d_ws;
    _Float16* bufH16 = (_Float16*)w; w += (size_t)N * 128 * sizeof(_Float16);
    _Float16* Wt1    = (_Float16*)w; w += (size_t)128 * 128 * sizeof(_Float16);
    _Float16* Wt2    = (_Float16*)w; w += (size_t)128 * 128 * sizeof(_Float16);
    float* asrc = (float*)w;   w += (size_t)N * 4 * sizeof(float);
    float* adst = (float*)w;   w += (size_t)N * 4 * sizeof(float);
    int* g_cnt   = (int*)w;    w += (size_t)ncnt * sizeof(int);
    int* incl    = (int*)w;    w += (size_t)ncnt * sizeof(int);
    int* offs    = (int*)w;    w += (size_t)(ncnt + 1) * sizeof(int);
    int* sums    = (int*)w;    w += 64 * sizeof(int);
    int* row_ptr = (int*)w;    w += (size_t)(N + 1) * sizeof(int);
    int2* binned = (int2*)w;   w += (size_t)E * sizeof(int2);
    int* csr     = (int*)w;    w += (size_t)(E + N) * sizeof(int);
    _Float16* bufA16 = (_Float16*)d_out;  // agg1 scratch; overwritten by agg2

    dim3 b256(256);
    const int nGemm = (N + 63) / 64;                  // 782
    const int nAlpha = (N + 3) / 4;                   // 12500
    dim3 gAgg(((((N + 1) / 2) + 3) / 4));             // 2 nodes/wave

    // ---- CSR build: hist -> scan -> offs ----
    hipLaunchKernelGGL(prep_kernel, dim3(NBLK1 + 128), b256, 0, stream, dst, g_cnt, E, chunk,
                       W1, W2, Wt1, Wt2, nbkt);
    hipLaunchKernelGGL(scan_tile_kernel, dim3(ntiles), b256, 0, stream, g_cnt, incl, sums, ncnt);
    hipLaunchKernelGGL(scan_sums_kernel, dim3(1), dim3(64), 0, stream, sums, ntiles);
    hipLaunchKernelGGL(offs_kernel, dim3((ncnt + 256) / 256 + 1), b256, 0, stream, incl, sums,
                       offs, ncnt);

    // ---- layer 1: gemm1 + bin scatter fused ----
    hipLaunchKernelGGL(gemm1_fused_kernel, dim3(nGemm + NBLK1), b256, 0, stream, x, Wt1,
                       bufH16, N, src, dst, offs, binned, E, chunk, nGemm, nbkt);
    hipLaunchKernelGGL(sort_alpha1_kernel, dim3(nbkt + nAlpha), b256, 0, stream, binned, offs,
                       row_ptr, csr, N, nbkt, bufH16, a_src1, a_dst1, asrc, adst);
    hipLaunchKernelGGL(agg1_kernel, gAgg, b256, 0, stream, bufH16, asrc, adst, row_ptr, csr, b1,
                       bufA16, N);

    // ---- layer 2 ----
    hipLaunchKernelGGL(gemm2_mfma_kernel, dim3(nGemm), b256, 0, stream, bufA16, Wt2, bufH16, N);
    hipLaunchKernelGGL(alpha2_kernel, dim3(nAlpha), b256, 0, stream, bufH16, a_src2, a_dst2,
                       asrc, adst, N);
    hipLaunchKernelGGL(agg2_kernel, gAgg, b256, 0, stream, bufH16, asrc, adst, row_ptr, csr, b2,
                       out, N);
}